// Round 14
// baseline (1239.611 us; speedup 1.0000x reference)
//
#include <hip/hip_runtime.h>
#include <hip/hip_bf16.h>

// ---------------------------------------------------------------------------
// KVCacheTransformerLayer on MI355X (gfx950). bf16 MFMA compute, fp32 spine.
// S=2048, PAST=2048, T=4096, B=2, H=16, hd=128, D=2048, DFF=8192, M=S*B=4096.
// ---------------------------------------------------------------------------

typedef __bf16 bf16x8 __attribute__((ext_vector_type(8)));
typedef float f32x4 __attribute__((ext_vector_type(4)));
typedef float f32x16 __attribute__((ext_vector_type(16)));
typedef unsigned int u32;

__device__ __forceinline__ unsigned short f2bf(float f) {
  union { float f; unsigned u; } v; v.f = f;
  return (unsigned short)((v.u + 0x7FFFu + ((v.u >> 16) & 1u)) >> 16);
}

__device__ __forceinline__ float bf2f(unsigned short u) {
  union { u32 u; float f; } v; v.u = (u32)u << 16;
  return v.f;
}

__device__ __forceinline__ float fexp2(float x) {
#if __has_builtin(__builtin_amdgcn_exp2f)
  return __builtin_amdgcn_exp2f(x);
#else
  float r;
  asm volatile("v_exp_f32 %0, %1\ns_nop 0" : "=v"(r) : "v"(x));
  return r;
#endif
}

// fast exact-enough GELU: x*e/(e+1), e = exp(2u). Max dev ~3e-4.
__device__ __forceinline__ float fast_gelu(float x) {
  const float u = 0.7978845608028654f * fmaf(0.044715f * x * x, x, x);
  const float e = fexp2(fminf(u * 2.885390081777927f, 126.f));
  float rcp;
  asm("v_rcp_f32 %0, %1" : "=v"(rcp) : "v"(e + 1.f));
  return x * e * rcp;
}

// async global->LDS, 16B per lane; LDS dest = wave-uniform base + lane*16
__device__ __forceinline__ void gl16(const void* g, void* l) {
  __builtin_amdgcn_global_load_lds((__attribute__((address_space(1))) void*)g,
                                   (__attribute__((address_space(3))) void*)l,
                                   16, 0, 0);
}

// ------------- weight convert fp32 [K,N] -> bf16 transposed [N,K] -----------
__global__ __launch_bounds__(256) void wconvT(const float* __restrict__ W,
                                              unsigned short* __restrict__ Wt,
                                              int K, int N) {
  __shared__ float tl[32][33];
  const int k0 = blockIdx.x * 32, n0 = blockIdx.y * 32;
  const int x = threadIdx.x & 31, y = threadIdx.x >> 5;
  for (int i = 0; i < 4; ++i)
    tl[y + i * 8][x] = W[(size_t)(k0 + y + i * 8) * N + n0 + x];
  __syncthreads();
  for (int i = 0; i < 4; ++i)
    Wt[(size_t)(n0 + y + i * 8) * K + k0 + x] = f2bf(tl[x][y + i * 8]);
}

// ---- fused prep: LN1 | kpack | vtrans | mask0 | wconvT4 in ONE dispatch ----
__global__ __launch_bounds__(256) void prep_k(
    const float* __restrict__ x, const float* __restrict__ ln1g,
    const float* __restrict__ ln1b, unsigned short* __restrict__ xn,
    const float* __restrict__ kc, unsigned short* __restrict__ kf,
    float* __restrict__ out_k,
    const float* __restrict__ vc, unsigned short* __restrict__ vft,
    float* __restrict__ out_v,
    const float* __restrict__ mask, u32* __restrict__ mflags,
    const float* __restrict__ q_w, const float* __restrict__ k_w,
    const float* __restrict__ v_w, const float* __restrict__ o_w,
    unsigned short* __restrict__ Wt) {
  __shared__ float tl[32][33];
  __shared__ float red[8];
  const int blk = blockIdx.x;
  const int tid = threadIdx.x;

  if (blk < 4096) {
    const int row = blk;
    const float4* xr = (const float4*)(x + (size_t)row * 2048);
    const float4 xa = xr[tid], xb = xr[tid + 256];
    float s = xa.x + xa.y + xa.z + xa.w + xb.x + xb.y + xb.z + xb.w;
    float q = xa.x * xa.x + xa.y * xa.y + xa.z * xa.z + xa.w * xa.w +
              xb.x * xb.x + xb.y * xb.y + xb.z * xb.z + xb.w * xb.w;
    for (int off = 32; off; off >>= 1) {
      s += __shfl_xor(s, off);
      q += __shfl_xor(q, off);
    }
    const int wv = tid >> 6, ln = tid & 63;
    if (ln == 0) { red[wv] = s; red[4 + wv] = q; }
    __syncthreads();
    s = red[0] + red[1] + red[2] + red[3];
    q = red[4] + red[5] + red[6] + red[7];
    const float mean = s * (1.f / 2048.f);
    const float rstd = rsqrtf(q * (1.f / 2048.f) - mean * mean + 1e-5f);
    const float4 g0 = ((const float4*)ln1g)[tid], g1 = ((const float4*)ln1g)[tid + 256];
    const float4 b0 = ((const float4*)ln1b)[tid], b1 = ((const float4*)ln1b)[tid + 256];
    ushort4 o0, o1;
    o0.x = f2bf((xa.x - mean) * rstd * g0.x + b0.x);
    o0.y = f2bf((xa.y - mean) * rstd * g0.y + b0.y);
    o0.z = f2bf((xa.z - mean) * rstd * g0.z + b0.z);
    o0.w = f2bf((xa.w - mean) * rstd * g0.w + b0.w);
    o1.x = f2bf((xb.x - mean) * rstd * g1.x + b1.x);
    o1.y = f2bf((xb.y - mean) * rstd * g1.y + b1.y);
    o1.z = f2bf((xb.z - mean) * rstd * g1.z + b1.z);
    o1.w = f2bf((xb.w - mean) * rstd * g1.w + b1.w);
    ((ushort4*)(xn + (size_t)row * 2048))[tid] = o0;
    ((ushort4*)(xn + (size_t)row * 2048))[tid + 256] = o1;
  } else if (blk < 12288) {
    const size_t e = ((size_t)(blk - 4096) * 256 + tid) * 4;
    const int r = (int)(e >> 11), c = (int)(e & 2047);
    const int t = r >> 1, b = r & 1, h = c >> 7, d = c & 127;
    const float4 v = *(const float4*)(kc + e);
    ushort4 o;
    o.x = f2bf(v.x); o.y = f2bf(v.y); o.z = f2bf(v.z); o.w = f2bf(v.w);
    *(ushort4*)(kf + ((size_t)((b * 16 + h) * 4096 + t)) * 128 + d) = o;
    *(float4*)(out_k + (size_t)r * 2048 + c) = v;
  } else if (blk < 20480) {
    const int i = blk - 12288;
    const int t0 = (i & 63) * 32, d0 = ((i >> 6) & 3) * 32, bh = i >> 8;
    const int b = bh >> 4, h = bh & 15;
    const int xx = tid & 31, yy = tid >> 5;
    for (int ii = 0; ii < 4; ++ii) {
      const int t = t0 + yy + ii * 8, d = d0 + xx;
      const float v = vc[((size_t)(t * 2 + b) * 16 + h) * 128 + d];
      tl[yy + ii * 8][xx] = v;
      out_v[((size_t)(t * 2 + b) * 16 + h) * 128 + d] = v;
    }
    __syncthreads();
    for (int ii = 0; ii < 4; ++ii) {
      const int d = d0 + yy + ii * 8, t = t0 + xx;
      vft[((size_t)bh * 128 + d) * 4096 + t] = f2bf(tl[xx][yy + ii * 8]);
    }
  } else if (blk < 20736) {
    const int mb = blk - 20480;
    const float4* p = (const float4*)mask + (size_t)mb * 8192 + tid;
    int nz = 0;
#pragma unroll
    for (int ii = 0; ii < 32; ++ii) {
      const float4 v = p[ii * 256];
      nz |= (v.x != 0.f) | (v.y != 0.f) | (v.z != 0.f) | (v.w != 0.f);
    }
    const int r = __syncthreads_or(nz);
    if (tid == 0) mflags[mb] = (u32)r;
  } else {
    const int i = blk - 20736;
    const int k0 = (i & 63) * 32, n0 = ((i >> 6) & 63) * 32, z = i >> 12;
    const float* W = z == 0 ? q_w : (z == 1 ? k_w : (z == 2 ? v_w : o_w));
    unsigned short* dst = Wt + (size_t)z * 2048 * 2048;
    const int xx = tid & 31, yy = tid >> 5;
    for (int ii = 0; ii < 4; ++ii)
      tl[yy + ii * 8][xx] = W[(size_t)(k0 + yy + ii * 8) * 2048 + n0 + xx];
    __syncthreads();
    for (int ii = 0; ii < 4; ++ii)
      dst[(size_t)(n0 + yy + ii * 8) * 2048 + k0 + xx] = f2bf(tl[xx][yy + ii * 8]);
  }
}

// ---- fused prep2: LN2 | wconvT(w1) | optional wconvT(w2) in ONE dispatch ---
__global__ __launch_bounds__(256) void prep2_k(
    const float* __restrict__ x1, const float* __restrict__ ln2g,
    const float* __restrict__ ln2b, unsigned short* __restrict__ hn,
    const float* __restrict__ w1, unsigned short* __restrict__ w1t,
    const float* __restrict__ w2, unsigned short* __restrict__ w2t) {
  __shared__ float tl[32][33];
  __shared__ float red[8];
  const int blk = blockIdx.x;
  const int tid = threadIdx.x;

  if (blk < 4096) {
    const int row = blk;
    const float4* xr = (const float4*)(x1 + (size_t)row * 2048);
    const float4 xa = xr[tid], xb = xr[tid + 256];
    float s = xa.x + xa.y + xa.z + xa.w + xb.x + xb.y + xb.z + xb.w;
    float q = xa.x * xa.x + xa.y * xa.y + xa.z * xa.z + xa.w * xa.w +
              xb.x * xb.x + xb.y * xb.y + xb.z * xb.z + xb.w * xb.w;
    for (int off = 32; off; off >>= 1) {
      s += __shfl_xor(s, off);
      q += __shfl_xor(q, off);
    }
    const int wv = tid >> 6, ln = tid & 63;
    if (ln == 0) { red[wv] = s; red[4 + wv] = q; }
    __syncthreads();
    s = red[0] + red[1] + red[2] + red[3];
    q = red[4] + red[5] + red[6] + red[7];
    const float mean = s * (1.f / 2048.f);
    const float rstd = rsqrtf(q * (1.f / 2048.f) - mean * mean + 1e-5f);
    const float4 g0 = ((const float4*)ln2g)[tid], g1 = ((const float4*)ln2g)[tid + 256];
    const float4 b0 = ((const float4*)ln2b)[tid], b1 = ((const float4*)ln2b)[tid + 256];
    ushort4 o0, o1;
    o0.x = f2bf((xa.x - mean) * rstd * g0.x + b0.x);
    o0.y = f2bf((xa.y - mean) * rstd * g0.y + b0.y);
    o0.z = f2bf((xa.z - mean) * rstd * g0.z + b0.z);
    o0.w = f2bf((xa.w - mean) * rstd * g0.w + b0.w);
    o1.x = f2bf((xb.x - mean) * rstd * g1.x + b1.x);
    o1.y = f2bf((xb.y - mean) * rstd * g1.y + b1.y);
    o1.z = f2bf((xb.z - mean) * rstd * g1.z + b1.z);
    o1.w = f2bf((xb.w - mean) * rstd * g1.w + b1.w);
    ((ushort4*)(hn + (size_t)row * 2048))[tid] = o0;
    ((ushort4*)(hn + (size_t)row * 2048))[tid + 256] = o1;
  } else if (blk < 20480) {
    const int i = blk - 4096;
    const int k0 = (i & 63) * 32, n0 = (i >> 6) * 32;
    const int xx = tid & 31, yy = tid >> 5;
    for (int ii = 0; ii < 4; ++ii)
      tl[yy + ii * 8][xx] = w1[(size_t)(k0 + yy + ii * 8) * 8192 + n0 + xx];
    __syncthreads();
    for (int ii = 0; ii < 4; ++ii)
      w1t[(size_t)(n0 + yy + ii * 8) * 2048 + k0 + xx] = f2bf(tl[xx][yy + ii * 8]);
  } else {
    const int i = blk - 20480;
    const int k0 = (i & 255) * 32, n0 = (i >> 8) * 32;
    const int xx = tid & 31, yy = tid >> 5;
    for (int ii = 0; ii < 4; ++ii)
      tl[yy + ii * 8][xx] = w2[(size_t)(k0 + yy + ii * 8) * 2048 + n0 + xx];
    __syncthreads();
    for (int ii = 0; ii < 4; ++ii)
      w2t[(size_t)(n0 + yy + ii * 8) * 8192 + k0 + xx] = f2bf(tl[xx][yy + ii * 8]);
  }
}

// --------- 256x256 8-phase GEMM (T2+T3+T4+T5), BK=64, 8 waves (2x4) ---------
// EPI: 0 = QKV packed outputs, 2 = GELU bf16 out via LDS-transposed epilogue.
template <int TAG, int EPI>
__global__ __launch_bounds__(512, 2) void gemm8p(
    const unsigned short* __restrict__ A, const unsigned short* __restrict__ Bt,
    const float* __restrict__ bias, const float* __restrict__ bias2,
    const float* __restrict__ bias3,
    float* __restrict__ Cf, unsigned short* __restrict__ Cb,
    float* __restrict__ of2, unsigned short* __restrict__ pb2,
    unsigned short* __restrict__ pb3, int N, int K) {
  __shared__ unsigned short sA[2][256 * 64];   // 64 KB
  __shared__ unsigned short sB[2][256 * 64];   // 64 KB
  const int tid = threadIdx.x;
  const int wv = tid >> 6, ln = tid & 63;
  const int wm = wv >> 2, wn = wv & 3;         // 2 x 4 waves
  const int nwg = gridDim.x;
  const int bid = blockIdx.x;
  const int wk = (bid & 7) * (nwg >> 3) + (bid >> 3);
  const int nmt = 16;                          // M/256
  const int m0 = (wk & (nmt - 1)) * 256, n0 = (wk / nmt) * 256;
  const int NT = K >> 6, NI = NT >> 1;

  f32x4 acc[8][4] = {};
  bf16x8 af[4][2], bfr[2][2];

  auto ST = [&](int t, int which, int bb) {
    if (t >= NT) return;
    const unsigned short* G = (which < 2) ? A : Bt;
    const int base0 = ((which < 2) ? m0 : n0) + (which & 1) * 128;
    char* dst = (char*)((which < 2) ? &sA[bb][0] : &sB[bb][0]) + (which & 1) * 16384;
    const size_t kb = (size_t)t * 64;
#pragma unroll
    for (int c = 0; c < 2; ++c) {
      const int o = tid * 16 + c * 8192;
      const int row = o >> 7;
      const int cb = (o & 127) ^ ((row & 7) << 4);
      gl16((const char*)G + ((size_t)(base0 + row) * K + kb) * 2 + cb, dst + o);
    }
  };
  auto LDA = [&](int bb, int mh) {
    const char* base = (const char*)&sA[bb][0];
#pragma unroll
    for (int i = 0; i < 4; ++i) {
      const int r = wm * 128 + mh * 64 + i * 16 + (ln & 15);
#pragma unroll
      for (int kk = 0; kk < 2; ++kk) {
        int aa = (r << 7) + ((ln >> 4) << 4) + kk * 64;
        aa ^= (r & 7) << 4;
        af[i][kk] = *(const bf16x8*)(base + aa);
      }
    }
  };
  auto LDB = [&](int bb, int nh) {
    const char* base = (const char*)&sB[bb][0];
#pragma unroll
    for (int j = 0; j < 2; ++j) {
      const int r = wn * 64 + nh * 32 + j * 16 + (ln & 15);
#pragma unroll
      for (int kk = 0; kk < 2; ++kk) {
        int aa = (r << 7) + ((ln >> 4) << 4) + kk * 64;
        aa ^= (r & 7) << 4;
        bfr[j][kk] = *(const bf16x8*)(base + aa);
      }
    }
  };
  auto MM = [&](int mh, int nh) {
    __builtin_amdgcn_s_setprio(1);
#pragma unroll
    for (int i = 0; i < 4; ++i)
#pragma unroll
      for (int j = 0; j < 2; ++j)
#pragma unroll
        for (int kk = 0; kk < 2; ++kk)
          acc[mh * 4 + i][nh * 2 + j] = __builtin_amdgcn_mfma_f32_16x16x32_bf16(
              af[i][kk], bfr[j][kk], acc[mh * 4 + i][nh * 2 + j], 0, 0, 0);
    __builtin_amdgcn_s_setprio(0);
  };
#define BAR() __builtin_amdgcn_s_barrier()
#define VM2() asm volatile("s_waitcnt vmcnt(2)" ::: "memory")
#define VM0() asm volatile("s_waitcnt vmcnt(0)" ::: "memory")

  ST(0, 0, 0); ST(0, 1, 0); ST(0, 2, 0); ST(0, 3, 0); ST(1, 0, 1);
  VM2();
  BAR();

#pragma unroll 1
  for (int it = 0; it < NI; ++it) {
    const int t1 = 2 * it + 1, t2 = 2 * it + 2, t3 = 2 * it + 3;
    const bool lastit = (it == NI - 1);
    LDA(0, 0); LDB(0, 0); ST(t1, 1, 1); BAR(); MM(0, 0); BAR();   // P1
    LDB(0, 1);            ST(t1, 2, 1); BAR(); MM(0, 1); BAR();   // P2
    LDA(0, 1);            ST(t1, 3, 1); BAR(); MM(1, 1); BAR();   // P3
    LDB(0, 0);            ST(t2, 0, 0); BAR(); MM(1, 0);          // P4
    if (lastit) VM0(); else VM2();
    BAR();
    LDA(1, 0); LDB(1, 0); ST(t2, 1, 0); BAR(); MM(0, 0); BAR();   // P5
    LDB(1, 1);            ST(t2, 2, 0); BAR(); MM(0, 1); BAR();   // P6
    LDA(1, 1);            ST(t2, 3, 0); BAR(); MM(1, 1); BAR();   // P7
    LDB(1, 0);            ST(t3, 0, 1); BAR(); MM(1, 0);          // P8
    if (!lastit) VM2();
    BAR();
  }
#undef BAR
#undef VM2
#undef VM0

  const int lr = (ln >> 4) << 2, lc = ln & 15;
  if (EPI == 0) {
    const int seg = n0 >> 11;
    const float* bp = seg == 0 ? bias : (seg == 1 ? bias2 : bias3);
#pragma unroll
    for (int f = 0; f < 8; ++f) {
#pragma unroll
      for (int j = 0; j < 4; ++j) {
        const int nn = (n0 & 2047) + wn * 64 + j * 16 + lc;
        const int h = nn >> 7, d = nn & 127;
        const float bv = bp[nn];
#pragma unroll
        for (int r = 0; r < 4; ++r) {
          const int m = m0 + wm * 128 + f * 16 + lr + r;
          const int s = m >> 1, b = m & 1;
          const float v = acc[f][j][r] + bv;
          if (seg == 0) {
            Cb[((size_t)(b * 16 + h) * 2048 + s) * 128 + d] = f2bf(v);
          } else if (seg == 1) {
            pb2[((size_t)(b * 16 + h) * 4096 + 2048 + s) * 128 + d] = f2bf(v);
            Cf[((size_t)((2048 + s) * 2 + b) * 16 + h) * 128 + d] = v;
          } else {
            pb3[((size_t)(b * 16 + h) * 128 + d) * 4096 + 2048 + s] = f2bf(v);
            of2[((size_t)((2048 + s) * 2 + b) * 16 + h) * 128 + d] = v;
          }
        }
      }
    }
  } else {
    // EPI==2: fast-GELU -> per-wave LDS tile -> coalesced bf16x8 stores
    char* wbase = (wv < 4) ? (char*)&sA[0][0] + wv * 16384
                           : (char*)&sB[0][0] + (wv - 4) * 16384;
#pragma unroll
    for (int f = 0; f < 8; ++f) {
#pragma unroll
      for (int j = 0; j < 4; ++j) {
        const int nl = j * 16 + lc;
        const float bv = bias[n0 + wn * 64 + nl];
#pragma unroll
        for (int r = 0; r < 4; ++r) {
          const int ml = f * 16 + lr + r;
          const float v = fast_gelu(acc[f][j][r] + bv);
          *(unsigned short*)(wbase + ml * 128 + ((nl * 2) ^ ((ml & 7) << 4))) =
              f2bf(v);
        }
      }
    }
    __syncthreads();
#pragma unroll
    for (int p = 0; p < 16; ++p) {
      const int row = p * 16 + (tid >> 5);
      const int nn = (tid & 31) * 8;
      const int wvv = (row >> 7) * 4 + (nn >> 6);
      const char* rb = (wvv < 4) ? (const char*)&sA[0][0] + wvv * 16384
                                 : (const char*)&sB[0][0] + (wvv - 4) * 16384;
      const int ml = row & 127, nl = nn & 63;
      const int4 val = *(const int4*)(rb + ml * 128 + ((nl * 2) ^ ((ml & 7) << 4)));
      *(int4*)((char*)Cb + ((size_t)(m0 + row) * N + n0 + nn) * 2) = val;
    }
  }
}

// ---- 128x256 8-phase GEMM, BK=64, 8 waves (2x4, 64x64 each), 96 KB LDS -----
// EPI: 1 = fp32 out + residual. (O-proj / FFN2)
template <int TAG, int EPI>
__global__ __launch_bounds__(512, 2) void gemm8n(
    const unsigned short* __restrict__ A, const unsigned short* __restrict__ Bt,
    const float* __restrict__ bias, const float* __restrict__ Rsd,
    float* __restrict__ Cf, int N, int K) {
  __shared__ unsigned short sA[2][128 * 64];   // 32 KB
  __shared__ unsigned short sB[2][256 * 64];   // 64 KB
  const int tid = threadIdx.x;
  const int wv = tid >> 6, ln = tid & 63;
  const int wm = wv >> 2, wn = wv & 3;
  const int nwg = gridDim.x;
  const int bid = blockIdx.x;
  const int wk = (bid & 7) * (nwg >> 3) + (bid >> 3);
  const int m0 = (wk & 31) * 128, n0 = (wk >> 5) * 256;
  const int NT = K >> 6;

  f32x4 acc[4][4] = {};
  bf16x8 af[2][2], bfr[2][2];

  auto ST = [&](int t, int which, int bb) {
    if (t >= NT) return;
    const unsigned short* G = (which == 0) ? A : Bt;
    const int base0 = (which == 0) ? m0 : (which == 1 ? n0 : n0 + 128);
    char* dst = (which == 0) ? (char*)&sA[bb][0]
                             : (char*)&sB[bb][0] + (which - 1) * 16384;
    const size_t kb = (size_t)t * 64;
#pragma unroll
    for (int c = 0; c < 2; ++c) {
      const int o = tid * 16 + c * 8192;
      const int row = o >> 7;
      const int cb = (o & 127) ^ ((row & 7) << 4);
      gl16((const char*)G + ((size_t)(base0 + row) * K + kb) * 2 + cb, dst + o);
    }
  };
  auto LDA = [&](int bb, int mh) {
    const char* base = (const char*)&sA[bb][0];
#pragma unroll
    for (int i = 0; i < 2; ++i) {
      const int r = wm * 64 + mh * 32 + i * 16 + (ln & 15);
#pragma unroll
      for (int kk = 0; kk < 2; ++kk) {
        int aa = (r << 7) + ((ln >> 4) << 4) + kk * 64;
        aa ^= (r & 7) << 4;
        af[i][kk] = *(const bf16x8*)(base + aa);
      }
    }
  };
  auto LDB = [&](int bb, int nh) {
    const char* base = (const char*)&sB[bb][0];
#pragma unroll
    for (int j = 0; j < 2; ++j) {
      const int r = wn * 64 + nh * 32 + j * 16 + (ln & 15);
#pragma unroll
      for (int kk = 0; kk < 2; ++kk) {
        int aa = (r << 7) + ((ln >> 4) << 4) + kk * 64;
        aa ^= (r & 7) << 4;
        bfr[j][kk] = *(const bf16x8*)(base + aa);
      }
    }
  };
  auto MM = [&](int mh, int nh) {
    __builtin_amdgcn_s_setprio(1);
#pragma unroll
    for (int i = 0; i < 2; ++i)
#pragma unroll
      for (int j = 0; j < 2; ++j)
#pragma unroll
        for (int kk = 0; kk < 2; ++kk)
          acc[mh * 2 + i][nh * 2 + j] = __builtin_amdgcn_mfma_f32_16x16x32_bf16(
              af[i][kk], bfr[j][kk], acc[mh * 2 + i][nh * 2 + j], 0, 0, 0);
    __builtin_amdgcn_s_setprio(0);
  };
#define BAR() __builtin_amdgcn_s_barrier()
#define VM2() asm volatile("s_waitcnt vmcnt(2)" ::: "memory")
#define VM0() asm volatile("s_waitcnt vmcnt(0)" ::: "memory")

  ST(0, 0, 0); ST(0, 1, 0); ST(0, 2, 0); ST(1, 0, 1);
  VM2();
  BAR();

#pragma unroll 1
  for (int t = 0; t < NT; ++t) {
    const int cur = t & 1;
    LDA(cur, 0); LDB(cur, 0); ST(t + 1, 1, cur ^ 1); BAR(); MM(0, 0); BAR();
    LDB(cur, 1); ST(t + 1, 2, cur ^ 1); BAR(); MM(0, 1); BAR();
    LDA(cur, 1); BAR(); MM(1, 1); BAR();
    LDB(cur, 0); ST(t + 2, 0, cur); BAR(); MM(1, 0);
    if (t >= NT - 2) VM0(); else VM2();
    BAR();
  }
#undef BAR
#undef VM2
#undef VM0

  const int lr = (ln >> 4) << 2, lc = ln & 15;
#pragma unroll
  for (int i = 0; i < 4; ++i) {
#pragma unroll
    for (int j = 0; j < 4; ++j) {
      const int n = n0 + wn * 64 + j * 16 + lc;
      const float bv = bias[n];
#pragma unroll
      for (int r = 0; r < 4; ++r) {
        const int m = m0 + wm * 64 + i * 16 + lr + r;
        const float v = acc[i][j][r] + bv + Rsd[(size_t)m * N + n];
        Cf[(size_t)m * N + n] = v;
      }
    }
  }
}

// --------- T-split flash attention: grid (16, 32, 2), 4 blocks/CU ----------
// Single-buffered K (16KB) + V (16KB) = 32 KB LDS; split-phase staging with
// counted vmcnt(4); partial (unnormalized O bf16, m/l f32) per T-half.
__global__ __launch_bounds__(256, 4) void attn7(
    const unsigned short* __restrict__ Q,   // [B*H, S, 128] bf16
    const unsigned short* __restrict__ Kf,  // [B*H, T, 128] bf16
    const unsigned short* __restrict__ Vt,  // [B*H, 128, T] bf16
    const float* __restrict__ mask,         // [S, T] fp32
    const u32* __restrict__ flags,          // 256 zero-detect flags
    unsigned short* __restrict__ pO0,       // [32][2048][128] bf16 (th=0)
    unsigned short* __restrict__ pO1,       // [32][2048][128] bf16 (th=1)
    float* __restrict__ pml) {              // [2 th][2 ml][65536] f32
  __shared__ __attribute__((aligned(16))) char smem[32768];  // sK@0, sV@16384
  const int tid = threadIdx.x;
  const int wv = tid >> 6;
  const int ln = tid & 63;
  const int q = ln & 31;
  const int hi = ln >> 5;
  const int sw = (q & 7) << 4;
  const int bh = blockIdx.y;
  const int th = blockIdx.z;
  const int s0w = blockIdx.x * 128 + wv * 32;

  const int mnz = __syncthreads_or((int)flags[tid]);

  bf16x8 qreg[8];
  {
    const char* qsrc = (const char*)Q +
        ((size_t)bh * 2048 + s0w + q) * 256 + (hi << 4);
#pragma unroll
    for (int kk = 0; kk < 8; ++kk) qreg[kk] = *(const bf16x8*)(qsrc + kk * 32);
  }

  const char* kp[8];
  const char* vp[4];
#pragma unroll
  for (int kk = 0; kk < 8; ++kk)
    kp[kk] = smem + (q << 8) + (((kk << 5) + (hi << 4)) ^ sw);
#pragma unroll
  for (int kk = 0; kk < 4; ++kk)
    vp[kk] = smem + 16384 + (q << 7) + (((kk << 5) + (hi << 4)) ^ sw);

  const char* Kg;
  const char* Vg;
  {
    const int oo = tid * 16;
    const int kr = oo >> 8, kc = oo & 255;
    Kg = (const char*)Kf + (size_t)bh * 4096 * 256 + (size_t)th * 2048 * 256 +
         (size_t)kr * 256 + (kc ^ ((kr & 7) << 4));
    const int vr = oo >> 7, vc = oo & 127;
    Vg = (const char*)Vt + (size_t)bh * 128 * 8192 + (size_t)vr * 8192 +
         (size_t)th * 4096 + (vc ^ ((vr & 7) << 4));
  }
  char* kdst = smem + tid * 16;
  char* vdst = smem + 16384 + tid * 16;

#define STGK()                                                  \
  do {                                                          \
    _Pragma("unroll") for (int is = 0; is < 4; ++is)            \
        gl16(Kg + is * 4096, kdst + is * 4096);                 \
    Kg += 16384;                                                \
  } while (0)
#define STGV()                                                  \
  do {                                                          \
    _Pragma("unroll") for (int is = 0; is < 4; ++is)            \
        gl16(Vg + (size_t)is * 262144, vdst + is * 4096);       \
    Vg += 128;                                                  \
  } while (0)
#define BARR() __builtin_amdgcn_s_barrier()
#define VMW4() asm volatile("s_waitcnt vmcnt(4)" ::: "memory")
#define VMW0() asm volatile("s_waitcnt vmcnt(0)" ::: "memory")

  f32x16 acc[4] = {};
  float m = -1e30f, l = 0.f;
  const float KLOG = 0.127517445f;   // (1/sqrt(128)) * log2(e)

  STGK(); STGV();   // tile 0: 8 loads outstanding
#pragma unroll 1
  for (int it = 0; it < 32; ++it) {
    VMW4();          // K(it) landed; V(it) still in flight
    BARR();
    // QK^T with 4 independent depth-4 MFMA chains
    f32x16 sc0, sc1;
    {
      f32x16 za = {}, zb = {}, zc = {}, zd = {};
      __builtin_amdgcn_s_setprio(1);
#pragma unroll
      for (int kk = 0; kk < 4; ++kk) {
        za = __builtin_amdgcn_mfma_f32_32x32x16_bf16(
            *(const bf16x8*)(kp[kk]), qreg[kk], za, 0, 0, 0);
        zb = __builtin_amdgcn_mfma_f32_32x32x16_bf16(
            *(const bf16x8*)(kp[kk + 4]), qreg[kk + 4], zb, 0, 0, 0);
        zc = __builtin_amdgcn_mfma_f32_32x32x16_bf16(
            *(const bf16x8*)(kp[kk] + 8192), qreg[kk], zc, 0, 0, 0);
        zd = __builtin_amdgcn_mfma_f32_32x32x16_bf16(
            *(const bf16x8*)(kp[kk + 4] + 8192), qreg[kk + 4], zd, 0, 0, 0);
      }
      __builtin_amdgcn_s_setprio(0);
      sc0 = za + zb;
      sc1 = zc + zd;
    }
    BARR();          // all waves done reading sK
    if (it < 31) STGK();   // stage K(it+1) into freed sK

    if (mnz) {
      const float rs = 11.313708498984761f;  // sqrt(128)
#pragma unroll
      for (int r = 0; r < 16; ++r) {
        const int tt = th * 2048 + it * 64 + ((r & 3) + ((r >> 2) << 3) + (hi << 2));
        sc0[r] = fmaf(mask[(size_t)(s0w + q) * 4096 + tt], rs, sc0[r]);
        sc1[r] = fmaf(mask[(size_t)(s0w + q) * 4096 + tt + 32], rs, sc1[r]);
      }
    }

    float pmax = sc0[0];
#pragma unroll
    for (int r = 1; r < 16; ++r) pmax = fmaxf(pmax, sc0[r]);
#pragma unroll
    for (int r = 0; r < 16; ++r) pmax = fmaxf(pmax, sc1[r]);
    pmax = fmaxf(pmax, __shfl_xor(pmax, 32));
    if (__any(pmax > m + 90.5f)) {
      const float mn = fmaxf(m, pmax);
      const float corr = fexp2((m - mn) * KLOG);
      m = mn; l *= corr;
#pragma unroll
      for (int d4 = 0; d4 < 4; ++d4)
#pragma unroll
        for (int e = 0; e < 16; ++e) acc[d4][e] *= corr;
    }
    const float mk = m * KLOG;
    float rsum = 0.f;
#pragma unroll
    for (int r = 0; r < 16; ++r) {
      const float e = fexp2(fmaf(sc0[r], KLOG, -mk));
      sc0[r] = e;
      rsum += e;
    }
#pragma unroll
    for (int r = 0; r < 16; ++r) {
      const float e = fexp2(fmaf(sc1[r], KLOG, -mk));
      sc1[r] = e;
      rsum += e;
    }
    rsum += __shfl_xor(rsum, 32);
    l += rsum;

    bf16x8 pw[4];
#pragma unroll
    for (int kk = 0; kk < 4; ++kk) {
      const int rb = (kk & 1) * 8;
      u32 w0, w1, w2, w3;
      if (kk < 2) {
        asm("v_cvt_pk_bf16_f32 %0, %1, %2" : "=v"(w0) : "v"(sc0[rb + 0]), "v"(sc0[rb + 1]));
        asm("v_cvt_pk_bf16_f32 %0, %1, %2" : "=v"(w1) : "v"(sc0[rb + 2]), "v"(sc0[rb + 3]));
        asm("v_cvt_pk_bf16_f32 %0, %1, %2" : "=v"(w2) : "v"(sc0[rb + 4]), "v"(sc0[rb + 5]));
        asm("v_cvt_pk_bf16_f32 %0, %1, %2" : "=v"(w3) : "v"(sc0[rb + 6]), "v"(sc0[rb + 7]));
      } else {
        asm("v_cvt_pk_bf16_f32 %0, %1, %2" : "=v"(w0) : "v"(sc1[rb + 0]), "v"(sc1[rb + 1]));
        asm("v_cvt_pk_bf16_f32 %0, %1, %2" : "=v"(w1) : "v"(sc1[rb + 2]), "v"(sc1[rb + 3]));
        asm("v_cvt_pk_bf16_f32 %0, %1, %2" : "=v"(w2) : "v"(sc1[rb + 4]), "v"(sc1[rb + 5]));
        asm("v_cvt_pk_bf16_f32 %0, %1, %2" : "=v"(w3) : "v"(sc1[rb + 6]), "v"(sc1[rb + 7]));
      }
      asm("v_permlane32_swap_b32 %0, %1" : "+v"(w0), "+v"(w2));
      asm("v_permlane32_swap_b32 %0, %1" : "+v"(w1), "+v"(w3));
      union { u32 u[4]; bf16x8 b; } pk;
      pk.u[0] = w0; pk.u[1] = w1; pk.u[2] = w2; pk.u[3] = w3;
      pw[kk] = pk.b;
    }

    if (it < 31) VMW4(); else VMW0();  // V(it) landed; K(it+1) in flight
    BARR();
#pragma unroll
    for (int d4 = 0; d4 < 4; ++d4) {
      __builtin_amdgcn_s_setprio(1);
#pragma unroll
      for (int kk = 0; kk < 4; ++kk)
        acc[d4] = __builtin_amdgcn_mfma_f32_32x32x16_bf16(
            *(const bf16x8*)(vp[kk] + d4 * 4096), pw[kk], acc[d4], 0, 0, 0);
      __builtin_amdgcn_s_setprio(0);
    }
    BARR();          // all waves done reading sV
    if (it < 31) STGV();   // stage V(it+1) into freed sV
  }
#undef STGK
#undef STGV
#undef BARR
#undef VMW4
#undef VMW0

  // write unnormalized partial O (bf16) + m/l (f32, one lane per row)
  const int rg = bh * 2048 + s0w + q;
  unsigned short* pO = (th == 0) ? pO0 : pO1;
  unsigned short* orow = pO + (size_t)rg * 128;
#pragma unroll
  for (int d4 = 0; d4 < 4; ++d4)
#pragma unroll
    for (int rq = 0; rq < 4; ++rq) {
      ushort4 o;
      o.x = f2bf(acc[d4][rq * 4 + 0]);
      o.y = f2bf(acc[d4][rq * 4 + 1]);
      o.z = f2bf(acc[d4][rq * 4 + 2]);
      o.w = f2bf(acc[d4][rq * 4 + 3]);
      *(ushort4*)(orow + d4 * 32 + rq * 8 + hi * 4) = o;
    }
  if (hi == 0) {
    pml[(size_t)(th * 2 + 0) * 65536 + rg] = m;
    pml[(size_t)(th * 2 + 1) * 65536 + rg] = l;
  }
}

// ----------------- flash combine: merge the two T-halves -------------------
__global__ __launch_bounds__(256) void cmb_k(
    const unsigned short* __restrict__ pO0,
    const unsigned short* __restrict__ pO1,
    const float* __restrict__ pml,
    unsigned short* __restrict__ ctx) {
  const int e4 = (blockIdx.x * 256 + threadIdx.x) * 4;
  const int rg = e4 >> 7, d = e4 & 127;
  const int bh = rg >> 11, row = rg & 2047;
  const float m0 = pml[rg], l0 = pml[65536 + rg];
  const float m1 = pml[131072 + rg], l1 = pml[196608 + rg];
  const float KLOG = 0.127517445f;
  const float mm = fmaxf(m0, m1);
  const float s0 = fexp2((m0 - mm) * KLOG);
  const float s1 = fexp2((m1 - mm) * KLOG);
  const float inv = 1.f / (l0 * s0 + l1 * s1);
  const ushort4 a = *(const ushort4*)(pO0 + (size_t)rg * 128 + d);
  const ushort4 c = *(const ushort4*)(pO1 + (size_t)rg * 128 + d);
  ushort4 o;
  o.x = f2bf((bf2f(a.x) * s0 + bf2f(c.x) * s1) * inv);
  o.y = f2bf((bf2f(a.y) * s0 + bf2f(c.y) * s1) * inv);
  o.z = f2bf((bf2f(a.z) * s0 + bf2f(c.z) * s1) * inv);
  o.w = f2bf((bf2f(a.w) * s0 + bf2f(c.w) * s1) * inv);
  const int b = bh >> 4, h = bh & 15;
  *(ushort4*)(ctx + (size_t)(row * 2 + b) * 2048 + h * 128 + d) = o;
}

// ---------------------------------------------------------------------------
extern "C" void kernel_launch(void* const* d_in, const int* in_sizes, int n_in,
                              void* d_out, int out_size, void* d_ws, size_t ws_size,
                              hipStream_t stream) {
  const float* x    = (const float*)d_in[0];
  const float* kc   = (const float*)d_in[1];
  const float* vc   = (const float*)d_in[2];
  const float* mask = (const float*)d_in[3];
  const float* q_w  = (const float*)d_in[4];
  const float* q_b  = (const float*)d_in[5];
  const float* k_w  = (const float*)d_in[6];
  const float* k_b  = (const float*)d_in[7];
  const float* v_w  = (const float*)d_in[8];
  const float* v_b  = (const float*)d_in[9];
  const float* o_w  = (const float*)d_in[10];
  const float* o_b  = (const float*)d_in[11];
  const float* ln1g = (const float*)d_in[12];
  const float* ln1b = (const float*)d_in[13];
  const float* ln2g = (const float*)d_in[14];
  const float* ln2b = (const float*)d_in[15];
  const float* w1   = (const float*)d_in[16];
  const float* b1   = (const float*)d_in[17];
  const float* w2   = (const float*)d_in[18];
  const float* b2   = (const float*)d_in[19];

  float* out_x = (float*)d_out;                       // [S,B,D]
  float* out_k = out_x + (size_t)8388608;             // [T,B,H,hd]
  float* out_v = out_k + (size_t)16777216;            // [T,B,H,hd]

  // ws: [0,32M) kf | [32,64M) vft | [64,96M) Wt | [96,128M) x1 region.
  // During attention the x1 region hosts: mflags@+0(1KB), pml@+4KB(1MB),
  // pO1@+2MB(16MB). pO0 lives in d_out's xn region (dead after QKV GEMM).
  // ctx goes to d_out's qb region (dead after attn). All overwritten later
  // in-order by x1 (O-proj) / hn (prep2) / out_x (FFN2).
  char* ws = (char*)d_ws;
  unsigned short* kf  = (unsigned short*)(ws);
  unsigned short* vft = (unsigned short*)(ws + 33554432);
  unsigned short* Wt  = (unsigned short*)(ws + 67108864);
  float*          x1  = (float*)(ws + 100663296);
  unsigned short* mid = (unsigned short*)ws;
  u32*   mflags = (u32*)(ws + 100663296);
  float* pml    = (float*)(ws + 100663296 + 4096);
  unsigned short* pO1 = (unsigned short*)(ws + 100663296 + 2097152);

  unsigned short* xn  = (unsigned short*)d_out;                     // bf16 16MB
  unsigned short* pO0 = xn;                                         // after QKV
  unsigned short* qb  = (unsigned short*)((char*)d_out + 16777216); // Q bf16
  unsigned short* ctx = qb;                                         // after attn
  unsigned short* hn  = qb;                                         // after O-proj

  const bool bigws = ws_size >= (size_t)167772160;              // >= 160 MiB
  unsigned short* w2t = bigws ? (unsigned short*)(ws + 134217728) : Wt;

  const dim3 b256(256);

  prep_k<<<37120, b256, 0, stream>>>(x, ln1g, ln1b, xn, kc, kf, out_k,
                                     vc, vft, out_v, mask, mflags,
                                     q_w, k_w, v_w, o_w, Wt);

  gemm8p<0, 0><<<384, dim3(512), 0, stream>>>(
      xn, Wt, q_b, k_b, v_b, out_k, qb, out_v, kf, vft, 6144, 2048);

  attn7<<<dim3(16, 32, 2), b256, 0, stream>>>(qb, kf, vft, mask, mflags,
                                              pO0, pO1, pml);
  cmb_k<<<8192, b256, 0, stream>>>(pO0, pO1, pml, ctx);

  gemm8n<1, 1><<<256, dim3(512), 0, stream>>>(
      ctx, Wt + (size_t)6144 * 2048, o_b, x, x1, 2048, 2048);

  prep2_k<<<bigws ? 36864 : 20480, b256, 0, stream>>>(
      x1, ln2g, ln2b, hn, w1, Wt, w2, w2t);

  gemm8p<2, 2><<<512, dim3(512), 0, stream>>>(
      hn, Wt, b1, nullptr, nullptr, nullptr, mid, nullptr, nullptr, nullptr,
      8192, 2048);

  if (!bigws) wconvT<<<dim3(256, 64), b256, 0, stream>>>(w2, Wt, 8192, 2048);

  gemm8n<3, 1><<<256, dim3(512), 0, stream>>>(
      mid, w2t, b2, x1, out_x, 2048, 8192);
}

// Round 15
// 796.751 us; speedup vs baseline: 1.5558x; 1.5558x over previous
//
#include <hip/hip_runtime.h>
#include <hip/hip_bf16.h>

// ---------------------------------------------------------------------------
// KVCacheTransformerLayer on MI355X (gfx950). bf16 MFMA compute, fp32 spine.
// S=2048, PAST=2048, T=4096, B=2, H=16, hd=128, D=2048, DFF=8192, M=S*B=4096.
// ---------------------------------------------------------------------------

typedef __bf16 bf16x8 __attribute__((ext_vector_type(8)));
typedef float f32x4 __attribute__((ext_vector_type(4)));
typedef float f32x16 __attribute__((ext_vector_type(16)));
typedef unsigned int u32;

__device__ __forceinline__ unsigned short f2bf(float f) {
  union { float f; unsigned u; } v; v.f = f;
  return (unsigned short)((v.u + 0x7FFFu + ((v.u >> 16) & 1u)) >> 16);
}

__device__ __forceinline__ float fexp2(float x) {
#if __has_builtin(__builtin_amdgcn_exp2f)
  return __builtin_amdgcn_exp2f(x);
#else
  float r;
  asm volatile("v_exp_f32 %0, %1\ns_nop 0" : "=v"(r) : "v"(x));
  return r;
#endif
}

// fast exact-enough GELU: x*e/(e+1), e = exp(2u). Max dev ~3e-4.
__device__ __forceinline__ float fast_gelu(float x) {
  const float u = 0.7978845608028654f * fmaf(0.044715f * x * x, x, x);
  const float e = fexp2(fminf(u * 2.885390081777927f, 126.f));
  float rcp;
  asm("v_rcp_f32 %0, %1" : "=v"(rcp) : "v"(e + 1.f));
  return x * e * rcp;
}

// async global->LDS, 16B per lane; LDS dest = wave-uniform base + lane*16
__device__ __forceinline__ void gl16(const void* g, void* l) {
  __builtin_amdgcn_global_load_lds((__attribute__((address_space(1))) void*)g,
                                   (__attribute__((address_space(3))) void*)l,
                                   16, 0, 0);
}

// ------------- weight convert fp32 [K,N] -> bf16 transposed [N,K] -----------
__global__ __launch_bounds__(256) void wconvT(const float* __restrict__ W,
                                              unsigned short* __restrict__ Wt,
                                              int K, int N) {
  __shared__ float tl[32][33];
  const int k0 = blockIdx.x * 32, n0 = blockIdx.y * 32;
  const int x = threadIdx.x & 31, y = threadIdx.x >> 5;
  for (int i = 0; i < 4; ++i)
    tl[y + i * 8][x] = W[(size_t)(k0 + y + i * 8) * N + n0 + x];
  __syncthreads();
  for (int i = 0; i < 4; ++i)
    Wt[(size_t)(n0 + y + i * 8) * K + k0 + x] = f2bf(tl[x][y + i * 8]);
}

// ---- fused prep: LN1 | kpack | vtrans | mask0 | wconvT4 in ONE dispatch ----
__global__ __launch_bounds__(256) void prep_k(
    const float* __restrict__ x, const float* __restrict__ ln1g,
    const float* __restrict__ ln1b, unsigned short* __restrict__ xn,
    const float* __restrict__ kc, unsigned short* __restrict__ kf,
    float* __restrict__ out_k,
    const float* __restrict__ vc, unsigned short* __restrict__ vft,
    float* __restrict__ out_v,
    const float* __restrict__ mask, u32* __restrict__ mflags,
    const float* __restrict__ q_w, const float* __restrict__ k_w,
    const float* __restrict__ v_w, const float* __restrict__ o_w,
    unsigned short* __restrict__ Wt) {
  __shared__ float tl[32][33];
  __shared__ float red[8];
  const int blk = blockIdx.x;
  const int tid = threadIdx.x;

  if (blk < 4096) {
    const int row = blk;
    const float4* xr = (const float4*)(x + (size_t)row * 2048);
    const float4 xa = xr[tid], xb = xr[tid + 256];
    float s = xa.x + xa.y + xa.z + xa.w + xb.x + xb.y + xb.z + xb.w;
    float q = xa.x * xa.x + xa.y * xa.y + xa.z * xa.z + xa.w * xa.w +
              xb.x * xb.x + xb.y * xb.y + xb.z * xb.z + xb.w * xb.w;
    for (int off = 32; off; off >>= 1) {
      s += __shfl_xor(s, off);
      q += __shfl_xor(q, off);
    }
    const int wv = tid >> 6, ln = tid & 63;
    if (ln == 0) { red[wv] = s; red[4 + wv] = q; }
    __syncthreads();
    s = red[0] + red[1] + red[2] + red[3];
    q = red[4] + red[5] + red[6] + red[7];
    const float mean = s * (1.f / 2048.f);
    const float rstd = rsqrtf(q * (1.f / 2048.f) - mean * mean + 1e-5f);
    const float4 g0 = ((const float4*)ln1g)[tid], g1 = ((const float4*)ln1g)[tid + 256];
    const float4 b0 = ((const float4*)ln1b)[tid], b1 = ((const float4*)ln1b)[tid + 256];
    ushort4 o0, o1;
    o0.x = f2bf((xa.x - mean) * rstd * g0.x + b0.x);
    o0.y = f2bf((xa.y - mean) * rstd * g0.y + b0.y);
    o0.z = f2bf((xa.z - mean) * rstd * g0.z + b0.z);
    o0.w = f2bf((xa.w - mean) * rstd * g0.w + b0.w);
    o1.x = f2bf((xb.x - mean) * rstd * g1.x + b1.x);
    o1.y = f2bf((xb.y - mean) * rstd * g1.y + b1.y);
    o1.z = f2bf((xb.z - mean) * rstd * g1.z + b1.z);
    o1.w = f2bf((xb.w - mean) * rstd * g1.w + b1.w);
    ((ushort4*)(xn + (size_t)row * 2048))[tid] = o0;
    ((ushort4*)(xn + (size_t)row * 2048))[tid + 256] = o1;
  } else if (blk < 12288) {
    const size_t e = ((size_t)(blk - 4096) * 256 + tid) * 4;
    const int r = (int)(e >> 11), c = (int)(e & 2047);
    const int t = r >> 1, b = r & 1, h = c >> 7, d = c & 127;
    const float4 v = *(const float4*)(kc + e);
    ushort4 o;
    o.x = f2bf(v.x); o.y = f2bf(v.y); o.z = f2bf(v.z); o.w = f2bf(v.w);
    *(ushort4*)(kf + ((size_t)((b * 16 + h) * 4096 + t)) * 128 + d) = o;
    *(float4*)(out_k + (size_t)r * 2048 + c) = v;
  } else if (blk < 20480) {
    const int i = blk - 12288;
    const int t0 = (i & 63) * 32, d0 = ((i >> 6) & 3) * 32, bh = i >> 8;
    const int b = bh >> 4, h = bh & 15;
    const int xx = tid & 31, yy = tid >> 5;
    for (int ii = 0; ii < 4; ++ii) {
      const int t = t0 + yy + ii * 8, d = d0 + xx;
      const float v = vc[((size_t)(t * 2 + b) * 16 + h) * 128 + d];
      tl[yy + ii * 8][xx] = v;
      out_v[((size_t)(t * 2 + b) * 16 + h) * 128 + d] = v;
    }
    __syncthreads();
    for (int ii = 0; ii < 4; ++ii) {
      const int d = d0 + yy + ii * 8, t = t0 + xx;
      vft[((size_t)bh * 128 + d) * 4096 + t] = f2bf(tl[xx][yy + ii * 8]);
    }
  } else if (blk < 20736) {
    const int mb = blk - 20480;
    const float4* p = (const float4*)mask + (size_t)mb * 8192 + tid;
    int nz = 0;
#pragma unroll
    for (int ii = 0; ii < 32; ++ii) {
      const float4 v = p[ii * 256];
      nz |= (v.x != 0.f) | (v.y != 0.f) | (v.z != 0.f) | (v.w != 0.f);
    }
    const int r = __syncthreads_or(nz);
    if (tid == 0) mflags[mb] = (u32)r;
  } else {
    const int i = blk - 20736;
    const int k0 = (i & 63) * 32, n0 = ((i >> 6) & 63) * 32, z = i >> 12;
    const float* W = z == 0 ? q_w : (z == 1 ? k_w : (z == 2 ? v_w : o_w));
    unsigned short* dst = Wt + (size_t)z * 2048 * 2048;
    const int xx = tid & 31, yy = tid >> 5;
    for (int ii = 0; ii < 4; ++ii)
      tl[yy + ii * 8][xx] = W[(size_t)(k0 + yy + ii * 8) * 2048 + n0 + xx];
    __syncthreads();
    for (int ii = 0; ii < 4; ++ii)
      dst[(size_t)(n0 + yy + ii * 8) * 2048 + k0 + xx] = f2bf(tl[xx][yy + ii * 8]);
  }
}

// ---- fused prep2: LN2 | wconvT(w1) | optional wconvT(w2) in ONE dispatch ---
__global__ __launch_bounds__(256) void prep2_k(
    const float* __restrict__ x1, const float* __restrict__ ln2g,
    const float* __restrict__ ln2b, unsigned short* __restrict__ hn,
    const float* __restrict__ w1, unsigned short* __restrict__ w1t,
    const float* __restrict__ w2, unsigned short* __restrict__ w2t) {
  __shared__ float tl[32][33];
  __shared__ float red[8];
  const int blk = blockIdx.x;
  const int tid = threadIdx.x;

  if (blk < 4096) {
    const int row = blk;
    const float4* xr = (const float4*)(x1 + (size_t)row * 2048);
    const float4 xa = xr[tid], xb = xr[tid + 256];
    float s = xa.x + xa.y + xa.z + xa.w + xb.x + xb.y + xb.z + xb.w;
    float q = xa.x * xa.x + xa.y * xa.y + xa.z * xa.z + xa.w * xa.w +
              xb.x * xb.x + xb.y * xb.y + xb.z * xb.z + xb.w * xb.w;
    for (int off = 32; off; off >>= 1) {
      s += __shfl_xor(s, off);
      q += __shfl_xor(q, off);
    }
    const int wv = tid >> 6, ln = tid & 63;
    if (ln == 0) { red[wv] = s; red[4 + wv] = q; }
    __syncthreads();
    s = red[0] + red[1] + red[2] + red[3];
    q = red[4] + red[5] + red[6] + red[7];
    const float mean = s * (1.f / 2048.f);
    const float rstd = rsqrtf(q * (1.f / 2048.f) - mean * mean + 1e-5f);
    const float4 g0 = ((const float4*)ln2g)[tid], g1 = ((const float4*)ln2g)[tid + 256];
    const float4 b0 = ((const float4*)ln2b)[tid], b1 = ((const float4*)ln2b)[tid + 256];
    ushort4 o0, o1;
    o0.x = f2bf((xa.x - mean) * rstd * g0.x + b0.x);
    o0.y = f2bf((xa.y - mean) * rstd * g0.y + b0.y);
    o0.z = f2bf((xa.z - mean) * rstd * g0.z + b0.z);
    o0.w = f2bf((xa.w - mean) * rstd * g0.w + b0.w);
    o1.x = f2bf((xb.x - mean) * rstd * g1.x + b1.x);
    o1.y = f2bf((xb.y - mean) * rstd * g1.y + b1.y);
    o1.z = f2bf((xb.z - mean) * rstd * g1.z + b1.z);
    o1.w = f2bf((xb.w - mean) * rstd * g1.w + b1.w);
    ((ushort4*)(hn + (size_t)row * 2048))[tid] = o0;
    ((ushort4*)(hn + (size_t)row * 2048))[tid + 256] = o1;
  } else if (blk < 20480) {
    const int i = blk - 4096;
    const int k0 = (i & 63) * 32, n0 = (i >> 6) * 32;
    const int xx = tid & 31, yy = tid >> 5;
    for (int ii = 0; ii < 4; ++ii)
      tl[yy + ii * 8][xx] = w1[(size_t)(k0 + yy + ii * 8) * 8192 + n0 + xx];
    __syncthreads();
    for (int ii = 0; ii < 4; ++ii)
      w1t[(size_t)(n0 + yy + ii * 8) * 2048 + k0 + xx] = f2bf(tl[xx][yy + ii * 8]);
  } else {
    const int i = blk - 20480;
    const int k0 = (i & 255) * 32, n0 = (i >> 8) * 32;
    const int xx = tid & 31, yy = tid >> 5;
    for (int ii = 0; ii < 4; ++ii)
      tl[yy + ii * 8][xx] = w2[(size_t)(k0 + yy + ii * 8) * 2048 + n0 + xx];
    __syncthreads();
    for (int ii = 0; ii < 4; ++ii)
      w2t[(size_t)(n0 + yy + ii * 8) * 8192 + k0 + xx] = f2bf(tl[xx][yy + ii * 8]);
  }
}

// --------- 256x256 8-phase GEMM (T2+T3+T4+T5), BK=64, 8 waves (2x4) ---------
// EPI: 0 = QKV packed outputs (LDS-gathered bf16 + direct fp32),
//      2 = GELU bf16 out via LDS-transposed epilogue.
template <int TAG, int EPI>
__global__ __launch_bounds__(512, 2) void gemm8p(
    const unsigned short* __restrict__ A, const unsigned short* __restrict__ Bt,
    const float* __restrict__ bias, const float* __restrict__ bias2,
    const float* __restrict__ bias3,
    float* __restrict__ Cf, unsigned short* __restrict__ Cb,
    float* __restrict__ of2, unsigned short* __restrict__ pb2,
    unsigned short* __restrict__ pb3, int N, int K) {
  // flat 128 KB: sA[bb] @ bb*32768, sB[bb] @ 65536 + bb*32768
  __shared__ __attribute__((aligned(16))) char smem[131072];
  const int tid = threadIdx.x;
  const int wv = tid >> 6, ln = tid & 63;
  const int wm = wv >> 2, wn = wv & 3;         // 2 x 4 waves
  const int nwg = gridDim.x;
  const int bid = blockIdx.x;
  const int wk = (bid & 7) * (nwg >> 3) + (bid >> 3);
  const int nmt = 16;                          // M/256
  const int m0 = (wk & (nmt - 1)) * 256, n0 = (wk / nmt) * 256;
  const int NT = K >> 6, NI = NT >> 1;

  f32x4 acc[8][4] = {};
  bf16x8 af[4][2], bfr[2][2];

  auto ST = [&](int t, int which, int bb) {
    if (t >= NT) return;
    const unsigned short* G = (which < 2) ? A : Bt;
    const int base0 = ((which < 2) ? m0 : n0) + (which & 1) * 128;
    char* dst = smem + ((which < 2) ? bb * 32768 : 65536 + bb * 32768) +
                (which & 1) * 16384;
    const size_t kb = (size_t)t * 64;
#pragma unroll
    for (int c = 0; c < 2; ++c) {
      const int o = tid * 16 + c * 8192;
      const int row = o >> 7;
      const int cb = (o & 127) ^ ((row & 7) << 4);
      gl16((const char*)G + ((size_t)(base0 + row) * K + kb) * 2 + cb, dst + o);
    }
  };
  auto LDA = [&](int bb, int mh) {
    const char* base = smem + bb * 32768;
#pragma unroll
    for (int i = 0; i < 4; ++i) {
      const int r = wm * 128 + mh * 64 + i * 16 + (ln & 15);
#pragma unroll
      for (int kk = 0; kk < 2; ++kk) {
        int aa = (r << 7) + ((ln >> 4) << 4) + kk * 64;
        aa ^= (r & 7) << 4;
        af[i][kk] = *(const bf16x8*)(base + aa);
      }
    }
  };
  auto LDB = [&](int bb, int nh) {
    const char* base = smem + 65536 + bb * 32768;
#pragma unroll
    for (int j = 0; j < 2; ++j) {
      const int r = wn * 64 + nh * 32 + j * 16 + (ln & 15);
#pragma unroll
      for (int kk = 0; kk < 2; ++kk) {
        int aa = (r << 7) + ((ln >> 4) << 4) + kk * 64;
        aa ^= (r & 7) << 4;
        bfr[j][kk] = *(const bf16x8*)(base + aa);
      }
    }
  };
  auto MM = [&](int mh, int nh) {
    __builtin_amdgcn_s_setprio(1);
#pragma unroll
    for (int i = 0; i < 4; ++i)
#pragma unroll
      for (int j = 0; j < 2; ++j)
#pragma unroll
        for (int kk = 0; kk < 2; ++kk)
          acc[mh * 4 + i][nh * 2 + j] = __builtin_amdgcn_mfma_f32_16x16x32_bf16(
              af[i][kk], bfr[j][kk], acc[mh * 4 + i][nh * 2 + j], 0, 0, 0);
    __builtin_amdgcn_s_setprio(0);
  };
#define BAR() __builtin_amdgcn_s_barrier()
#define VM2() asm volatile("s_waitcnt vmcnt(2)" ::: "memory")
#define VM0() asm volatile("s_waitcnt vmcnt(0)" ::: "memory")

  ST(0, 0, 0); ST(0, 1, 0); ST(0, 2, 0); ST(0, 3, 0); ST(1, 0, 1);
  VM2();
  BAR();

#pragma unroll 1
  for (int it = 0; it < NI; ++it) {
    const int t1 = 2 * it + 1, t2 = 2 * it + 2, t3 = 2 * it + 3;
    const bool lastit = (it == NI - 1);
    LDA(0, 0); LDB(0, 0); ST(t1, 1, 1); BAR(); MM(0, 0); BAR();   // P1
    LDB(0, 1);            ST(t1, 2, 1); BAR(); MM(0, 1); BAR();   // P2
    LDA(0, 1);            ST(t1, 3, 1); BAR(); MM(1, 1); BAR();   // P3
    LDB(0, 0);            ST(t2, 0, 0); BAR(); MM(1, 0);          // P4
    if (lastit) VM0(); else VM2();
    BAR();
    LDA(1, 0); LDB(1, 0); ST(t2, 1, 0); BAR(); MM(0, 0); BAR();   // P5
    LDB(1, 1);            ST(t2, 2, 0); BAR(); MM(0, 1); BAR();   // P6
    LDA(1, 1);            ST(t2, 3, 0); BAR(); MM(1, 1); BAR();   // P7
    LDB(1, 0);            ST(t3, 0, 1); BAR(); MM(1, 0);          // P8
    if (!lastit) VM2();
    BAR();
  }
#undef BAR
#undef VM2
#undef VM0

  const int lr = (ln >> 4) << 2, lc = ln & 15;
  if (EPI == 0) {
    // QKV packed. seg: 0=Q(bf16 qb), 1=K(bf16 kf + fp32 out_k),
    // 2=V(bf16 vft transposed + fp32 out_v). Block in one 2048-col segment.
    const int seg = n0 >> 11;
    const float* bp = seg == 0 ? bias : (seg == 1 ? bias2 : bias3);
    // (1) direct fp32 writes (affine rows, coalesced along nn)
    if (seg == 1 || seg == 2) {
#pragma unroll
      for (int f = 0; f < 8; ++f) {
#pragma unroll
        for (int j = 0; j < 4; ++j) {
          const int nn = (n0 & 2047) + wn * 64 + j * 16 + lc;
          const float bv = bp[nn];
#pragma unroll
          for (int r = 0; r < 4; ++r) {
            const int m = m0 + wm * 128 + f * 16 + lr + r;
            const float v = acc[f][j][r] + bv;
            // out row = (2048 + s)*2 + b = 4096 + m ; col = nn
            float* dstf = (seg == 1) ? Cf : of2;
            dstf[(size_t)(4096 + m) * 2048 + nn] = v;
          }
        }
      }
    }
    // (2) stage bias-added bf16 C-tile into LDS [ml 256][nl 256] (swizzled)
#pragma unroll
    for (int f = 0; f < 8; ++f) {
#pragma unroll
      for (int j = 0; j < 4; ++j) {
        const int nl = wn * 64 + j * 16 + lc;       // 0..255
        const float bv = bp[(n0 & 2047) + nl];
#pragma unroll
        for (int r = 0; r < 4; ++r) {
          const int ml = wm * 128 + f * 16 + lr + r;  // 0..255
          *(unsigned short*)(smem + ml * 512 + ((nl * 2) ^ ((ml & 7) << 4))) =
              f2bf(acc[f][j][r] + bv);
        }
      }
    }
    __syncthreads();
    const int h0 = (n0 & 2047) >> 7;                 // first head of tile
    if (seg == 0 || seg == 1) {
      // thread owns output row (b,h,s): ml = tid>>1, hl = tid&1
      const int ml = tid >> 1, hl = tid & 1;
      const int m = m0 + ml, s = m >> 1, b = m & 1, h = h0 + hl;
      char* drow = (seg == 0)
          ? (char*)Cb + ((size_t)(b * 16 + h) * 2048 + s) * 256
          : (char*)pb2 + ((size_t)(b * 16 + h) * 4096 + 2048 + s) * 256;
#pragma unroll
      for (int c = 0; c < 16; ++c) {
        const int4 val = *(const int4*)(
            smem + ml * 512 + ((hl * 256 + c * 16) ^ ((ml & 7) << 4)));
        *(int4*)(drow + c * 16) = val;
      }
    } else {
      // V transposed: thread owns (hl, d, b); gather LDS column, write t-run
      const int hl = tid >> 8, d = (tid >> 1) & 127, b = tid & 1;
      const int nl2 = (hl * 128 + d) * 2;
      char* drow = (char*)pb3 +
          ((size_t)((b * 16 + h0 + hl) * 128 + d) * 4096 + 2048 + (m0 >> 1)) * 2;
#pragma unroll
      for (int sc = 0; sc < 16; ++sc) {
        union { unsigned short u[8]; int4 v; } t8;
#pragma unroll
        for (int si = 0; si < 8; ++si) {
          const int ml = (sc * 8 + si) * 2 + b;
          t8.u[si] = *(const unsigned short*)(
              smem + ml * 512 + (nl2 ^ ((ml & 7) << 4)));
        }
        *(int4*)(drow + sc * 16) = t8.v;
      }
    }
  } else {
    // EPI==2: fast-GELU -> per-wave LDS tile -> coalesced bf16x8 stores
    char* wbase = smem + wv * 16384;
#pragma unroll
    for (int f = 0; f < 8; ++f) {
#pragma unroll
      for (int j = 0; j < 4; ++j) {
        const int nl = j * 16 + lc;
        const float bv = bias[n0 + wn * 64 + nl];
#pragma unroll
        for (int r = 0; r < 4; ++r) {
          const int ml = f * 16 + lr + r;
          const float v = fast_gelu(acc[f][j][r] + bv);
          *(unsigned short*)(wbase + ml * 128 + ((nl * 2) ^ ((ml & 7) << 4))) =
              f2bf(v);
        }
      }
    }
    __syncthreads();
#pragma unroll
    for (int p = 0; p < 16; ++p) {
      const int row = p * 16 + (tid >> 5);
      const int nn = (tid & 31) * 8;
      const int wvv = (row >> 7) * 4 + (nn >> 6);
      const char* rb = smem + wvv * 16384;
      const int ml = row & 127, nl = nn & 63;
      const int4 val = *(const int4*)(rb + ml * 128 + ((nl * 2) ^ ((ml & 7) << 4)));
      *(int4*)((char*)Cb + ((size_t)(m0 + row) * N + n0 + nn) * 2) = val;
    }
  }
}

// ---- 128x256 8-phase GEMM, BK=64, 8 waves (2x4, 64x64 each), 96 KB LDS -----
// EPI: 1 = fp32 out + residual. (O-proj / FFN2)
template <int TAG, int EPI>
__global__ __launch_bounds__(512, 2) void gemm8n(
    const unsigned short* __restrict__ A, const unsigned short* __restrict__ Bt,
    const float* __restrict__ bias, const float* __restrict__ Rsd,
    float* __restrict__ Cf, int N, int K) {
  __shared__ unsigned short sA[2][128 * 64];   // 32 KB
  __shared__ unsigned short sB[2][256 * 64];   // 64 KB
  const int tid = threadIdx.x;
  const int wv = tid >> 6, ln = tid & 63;
  const int wm = wv >> 2, wn = wv & 3;
  const int nwg = gridDim.x;
  const int bid = blockIdx.x;
  const int wk = (bid & 7) * (nwg >> 3) + (bid >> 3);
  const int m0 = (wk & 31) * 128, n0 = (wk >> 5) * 256;
  const int NT = K >> 6;

  f32x4 acc[4][4] = {};
  bf16x8 af[2][2], bfr[2][2];

  auto ST = [&](int t, int which, int bb) {
    if (t >= NT) return;
    const unsigned short* G = (which == 0) ? A : Bt;
    const int base0 = (which == 0) ? m0 : (which == 1 ? n0 : n0 + 128);
    char* dst = (which == 0) ? (char*)&sA[bb][0]
                             : (char*)&sB[bb][0] + (which - 1) * 16384;
    const size_t kb = (size_t)t * 64;
#pragma unroll
    for (int c = 0; c < 2; ++c) {
      const int o = tid * 16 + c * 8192;
      const int row = o >> 7;
      const int cb = (o & 127) ^ ((row & 7) << 4);
      gl16((const char*)G + ((size_t)(base0 + row) * K + kb) * 2 + cb, dst + o);
    }
  };
  auto LDA = [&](int bb, int mh) {
    const char* base = (const char*)&sA[bb][0];
#pragma unroll
    for (int i = 0; i < 2; ++i) {
      const int r = wm * 64 + mh * 32 + i * 16 + (ln & 15);
#pragma unroll
      for (int kk = 0; kk < 2; ++kk) {
        int aa = (r << 7) + ((ln >> 4) << 4) + kk * 64;
        aa ^= (r & 7) << 4;
        af[i][kk] = *(const bf16x8*)(base + aa);
      }
    }
  };
  auto LDB = [&](int bb, int nh) {
    const char* base = (const char*)&sB[bb][0];
#pragma unroll
    for (int j = 0; j < 2; ++j) {
      const int r = wn * 64 + nh * 32 + j * 16 + (ln & 15);
#pragma unroll
      for (int kk = 0; kk < 2; ++kk) {
        int aa = (r << 7) + ((ln >> 4) << 4) + kk * 64;
        aa ^= (r & 7) << 4;
        bfr[j][kk] = *(const bf16x8*)(base + aa);
      }
    }
  };
  auto MM = [&](int mh, int nh) {
    __builtin_amdgcn_s_setprio(1);
#pragma unroll
    for (int i = 0; i < 2; ++i)
#pragma unroll
      for (int j = 0; j < 2; ++j)
#pragma unroll
        for (int kk = 0; kk < 2; ++kk)
          acc[mh * 2 + i][nh * 2 + j] = __builtin_amdgcn_mfma_f32_16x16x32_bf16(
              af[i][kk], bfr[j][kk], acc[mh * 2 + i][nh * 2 + j], 0, 0, 0);
    __builtin_amdgcn_s_setprio(0);
  };
#define BAR() __builtin_amdgcn_s_barrier()
#define VM2() asm volatile("s_waitcnt vmcnt(2)" ::: "memory")
#define VM0() asm volatile("s_waitcnt vmcnt(0)" ::: "memory")

  ST(0, 0, 0); ST(0, 1, 0); ST(0, 2, 0); ST(1, 0, 1);
  VM2();
  BAR();

#pragma unroll 1
  for (int t = 0; t < NT; ++t) {
    const int cur = t & 1;
    LDA(cur, 0); LDB(cur, 0); ST(t + 1, 1, cur ^ 1); BAR(); MM(0, 0); BAR();
    LDB(cur, 1); ST(t + 1, 2, cur ^ 1); BAR(); MM(0, 1); BAR();
    LDA(cur, 1); BAR(); MM(1, 1); BAR();
    LDB(cur, 0); ST(t + 2, 0, cur); BAR(); MM(1, 0);
    if (t >= NT - 2) VM0(); else VM2();
    BAR();
  }
#undef BAR
#undef VM2
#undef VM0

  const int lr = (ln >> 4) << 2, lc = ln & 15;
#pragma unroll
  for (int i = 0; i < 4; ++i) {
#pragma unroll
    for (int j = 0; j < 4; ++j) {
      const int n = n0 + wn * 64 + j * 16 + lc;
      const float bv = bias[n];
#pragma unroll
      for (int r = 0; r < 4; ++r) {
        const int m = m0 + wm * 64 + i * 16 + lr + r;
        const float v = acc[i][j][r] + bv + Rsd[(size_t)m * N + n];
        Cf[(size_t)m * N + n] = v;
      }
    }
  }
}

// ------------- flash attention, 4 waves x 32 q-rows, KVBLK=64 ---------------
// attn6: counted-vmcnt pipeline + 4 independent depth-4 QK MFMA chains (ILP).
__global__ __launch_bounds__(256, 2) void attn6(
    const unsigned short* __restrict__ Q,   // [B*H, S, 128] bf16
    const unsigned short* __restrict__ Kf,  // [B*H, T, 128] bf16
    const unsigned short* __restrict__ Vt,  // [B*H, 128, T] bf16
    const float* __restrict__ mask,         // [S, T] fp32
    const u32* __restrict__ flags,          // 256 zero-detect flags
    unsigned short* __restrict__ ctx) {     // [(s,b), (h,d)] bf16
  __shared__ __attribute__((aligned(16))) char smem[65536];
  const int tid = threadIdx.x;
  const int wv = tid >> 6;
  const int ln = tid & 63;
  const int q = ln & 31;
  const int hi = ln >> 5;
  const int sw = (q & 7) << 4;
  const int bh = blockIdx.y;
  const int s0w = blockIdx.x * 128 + wv * 32;

  const int mnz = __syncthreads_or((int)flags[tid]);

  bf16x8 qreg[8];
  {
    const char* qsrc = (const char*)Q +
        ((size_t)bh * 2048 + s0w + q) * 256 + (hi << 4);
#pragma unroll
    for (int kk = 0; kk < 8; ++kk) qreg[kk] = *(const bf16x8*)(qsrc + kk * 32);
  }

  const char* kp[8];
  const char* vp[4];
#pragma unroll
  for (int kk = 0; kk < 8; ++kk)
    kp[kk] = smem + (q << 8) + (((kk << 5) + (hi << 4)) ^ sw);
#pragma unroll
  for (int kk = 0; kk < 4; ++kk)
    vp[kk] = smem + 32768 + (q << 7) + (((kk << 5) + (hi << 4)) ^ sw);

  const char* Kg;
  const char* Vg;
  {
    const int oo = tid * 16;
    const int kr = oo >> 8, kc = oo & 255;
    Kg = (const char*)Kf + (size_t)bh * 4096 * 256 + (size_t)kr * 256 +
         (kc ^ ((kr & 7) << 4));
    const int vr = oo >> 7, vc = oo & 127;
    Vg = (const char*)Vt + (size_t)bh * 128 * 8192 + (size_t)vr * 8192 +
         (vc ^ ((vr & 7) << 4));
  }
  char* kdst = smem + tid * 16;
  char* vdst = smem + 32768 + tid * 16;

#define STG(BUF)                                               \
  do {                                                         \
    _Pragma("unroll") for (int is = 0; is < 4; ++is) {         \
      gl16(Kg + is * 4096, kdst + (BUF) + is * 4096);          \
      gl16(Vg + (size_t)is * 262144, vdst + (BUF) + is * 4096);\
    }                                                          \
    Kg += 16384; Vg += 128;                                    \
  } while (0)
#define BARR() __builtin_amdgcn_s_barrier()
#define VMW8() asm volatile("s_waitcnt vmcnt(8)" ::: "memory")
#define VMW0() asm volatile("s_waitcnt vmcnt(0)" ::: "memory")

  f32x16 acc[4] = {};
  float m = -1e30f, l = 0.f;
  const float KLOG = 0.127517445f;   // (1/sqrt(128)) * log2(e)

  auto tile = [&](int BUF, int it) {
    f32x16 sc0, sc1;
    {
      f32x16 za = {}, zb = {}, zc = {}, zd = {};
      __builtin_amdgcn_s_setprio(1);
#pragma unroll
      for (int kk = 0; kk < 4; ++kk) {
        za = __builtin_amdgcn_mfma_f32_32x32x16_bf16(
            *(const bf16x8*)(kp[kk] + BUF), qreg[kk], za, 0, 0, 0);
        zb = __builtin_amdgcn_mfma_f32_32x32x16_bf16(
            *(const bf16x8*)(kp[kk + 4] + BUF), qreg[kk + 4], zb, 0, 0, 0);
        zc = __builtin_amdgcn_mfma_f32_32x32x16_bf16(
            *(const bf16x8*)(kp[kk] + BUF + 8192), qreg[kk], zc, 0, 0, 0);
        zd = __builtin_amdgcn_mfma_f32_32x32x16_bf16(
            *(const bf16x8*)(kp[kk + 4] + BUF + 8192), qreg[kk + 4], zd, 0, 0, 0);
      }
      __builtin_amdgcn_s_setprio(0);
      sc0 = za + zb;
      sc1 = zc + zd;
    }

    if (mnz) {
      const float rs = 11.313708498984761f;  // sqrt(128)
#pragma unroll
      for (int r = 0; r < 16; ++r) {
        const int tt = it * 64 + ((r & 3) + ((r >> 2) << 3) + (hi << 2));
        sc0[r] = fmaf(mask[(size_t)(s0w + q) * 4096 + tt], rs, sc0[r]);
        sc1[r] = fmaf(mask[(size_t)(s0w + q) * 4096 + tt + 32], rs, sc1[r]);
      }
    }

    float pmax = sc0[0];
#pragma unroll
    for (int r = 1; r < 16; ++r) pmax = fmaxf(pmax, sc0[r]);
#pragma unroll
    for (int r = 0; r < 16; ++r) pmax = fmaxf(pmax, sc1[r]);
    pmax = fmaxf(pmax, __shfl_xor(pmax, 32));
    if (__any(pmax > m + 90.5f)) {
      const float mn = fmaxf(m, pmax);
      const float corr = fexp2((m - mn) * KLOG);
      m = mn; l *= corr;
#pragma unroll
      for (int d4 = 0; d4 < 4; ++d4)
#pragma unroll
        for (int e = 0; e < 16; ++e) acc[d4][e] *= corr;
    }
    const float mk = m * KLOG;
    float rsum = 0.f;
#pragma unroll
    for (int r = 0; r < 16; ++r) {
      const float e = fexp2(fmaf(sc0[r], KLOG, -mk));
      sc0[r] = e;
      rsum += e;
    }
#pragma unroll
    for (int r = 0; r < 16; ++r) {
      const float e = fexp2(fmaf(sc1[r], KLOG, -mk));
      sc1[r] = e;
      rsum += e;
    }
    rsum += __shfl_xor(rsum, 32);
    l += rsum;

    bf16x8 pw[4];
#pragma unroll
    for (int kk = 0; kk < 4; ++kk) {
      const int rb = (kk & 1) * 8;
      u32 w0, w1, w2, w3;
      if (kk < 2) {
        asm("v_cvt_pk_bf16_f32 %0, %1, %2" : "=v"(w0) : "v"(sc0[rb + 0]), "v"(sc0[rb + 1]));
        asm("v_cvt_pk_bf16_f32 %0, %1, %2" : "=v"(w1) : "v"(sc0[rb + 2]), "v"(sc0[rb + 3]));
        asm("v_cvt_pk_bf16_f32 %0, %1, %2" : "=v"(w2) : "v"(sc0[rb + 4]), "v"(sc0[rb + 5]));
        asm("v_cvt_pk_bf16_f32 %0, %1, %2" : "=v"(w3) : "v"(sc0[rb + 6]), "v"(sc0[rb + 7]));
      } else {
        asm("v_cvt_pk_bf16_f32 %0, %1, %2" : "=v"(w0) : "v"(sc1[rb + 0]), "v"(sc1[rb + 1]));
        asm("v_cvt_pk_bf16_f32 %0, %1, %2" : "=v"(w1) : "v"(sc1[rb + 2]), "v"(sc1[rb + 3]));
        asm("v_cvt_pk_bf16_f32 %0, %1, %2" : "=v"(w2) : "v"(sc1[rb + 4]), "v"(sc1[rb + 5]));
        asm("v_cvt_pk_bf16_f32 %0, %1, %2" : "=v"(w3) : "v"(sc1[rb + 6]), "v"(sc1[rb + 7]));
      }
      asm("v_permlane32_swap_b32 %0, %1" : "+v"(w0), "+v"(w2));
      asm("v_permlane32_swap_b32 %0, %1" : "+v"(w1), "+v"(w3));
      union { u32 u[4]; bf16x8 b; } pk;
      pk.u[0] = w0; pk.u[1] = w1; pk.u[2] = w2; pk.u[3] = w3;
      pw[kk] = pk.b;
    }

#pragma unroll
    for (int d4 = 0; d4 < 4; ++d4) {
      __builtin_amdgcn_s_setprio(1);
#pragma unroll
      for (int kk = 0; kk < 4; ++kk)
        acc[d4] = __builtin_amdgcn_mfma_f32_32x32x16_bf16(
            *(const bf16x8*)(vp[kk] + BUF + d4 * 4096), pw[kk], acc[d4], 0, 0, 0);
      __builtin_amdgcn_s_setprio(0);
    }
  };

  STG(0);
  STG(16384);
#pragma unroll 1
  for (int it2 = 0; it2 < 31; ++it2) {
    VMW8(); BARR();
    tile(0, 2 * it2);
    BARR();
    STG(0);
    VMW8(); BARR();
    tile(16384, 2 * it2 + 1);
    BARR();
    STG(16384);
  }
  VMW8(); BARR();
  tile(0, 62);
  BARR();
  VMW0(); BARR();
  tile(16384, 63);
#undef STG
#undef BARR
#undef VMW8
#undef VMW0

  const float inv = 1.f / l;
  const int b = bh >> 4, h = bh & 15;
  unsigned short* crow = ctx + ((size_t)(s0w + q) * 2 + b) * 2048 + h * 128;
#pragma unroll
  for (int d4 = 0; d4 < 4; ++d4)
#pragma unroll
    for (int rq = 0; rq < 4; ++rq) {
      ushort4 o;
      o.x = f2bf(acc[d4][rq * 4 + 0] * inv);
      o.y = f2bf(acc[d4][rq * 4 + 1] * inv);
      o.z = f2bf(acc[d4][rq * 4 + 2] * inv);
      o.w = f2bf(acc[d4][rq * 4 + 3] * inv);
      *(ushort4*)(crow + d4 * 32 + rq * 8 + hi * 4) = o;
    }
}

// ---------------------------------------------------------------------------
extern "C" void kernel_launch(void* const* d_in, const int* in_sizes, int n_in,
                              void* d_out, int out_size, void* d_ws, size_t ws_size,
                              hipStream_t stream) {
  const float* x    = (const float*)d_in[0];
  const float* kc   = (const float*)d_in[1];
  const float* vc   = (const float*)d_in[2];
  const float* mask = (const float*)d_in[3];
  const float* q_w  = (const float*)d_in[4];
  const float* q_b  = (const float*)d_in[5];
  const float* k_w  = (const float*)d_in[6];
  const float* k_b  = (const float*)d_in[7];
  const float* v_w  = (const float*)d_in[8];
  const float* v_b  = (const float*)d_in[9];
  const float* o_w  = (const float*)d_in[10];
  const float* o_b  = (const float*)d_in[11];
  const float* ln1g = (const float*)d_in[12];
  const float* ln1b = (const float*)d_in[13];
  const float* ln2g = (const float*)d_in[14];
  const float* ln2b = (const float*)d_in[15];
  const float* w1   = (const float*)d_in[16];
  const float* b1   = (const float*)d_in[17];
  const float* w2   = (const float*)d_in[18];
  const float* b2   = (const float*)d_in[19];

  float* out_x = (float*)d_out;                       // [S,B,D]
  float* out_k = out_x + (size_t)8388608;             // [T,B,H,hd]
  float* out_v = out_k + (size_t)16777216;            // [T,B,H,hd]

  char* ws = (char*)d_ws;
  unsigned short* kf  = (unsigned short*)(ws);                  // bf16 [B,H,T,hd]
  unsigned short* vft = (unsigned short*)(ws + 33554432);       // bf16 [B,H,hd,T]
  unsigned short* Wt  = (unsigned short*)(ws + 67108864);       // bf16 [8192,2048]
  float*          x1  = (float*)(ws + 100663296);               // fp32 [4096,2048]
  unsigned short* mid = (unsigned short*)ws;                    // bf16 [4096,8192]
  u32* mflags = (u32*)(ws + 100663296);                         // 256 u32 flags

  unsigned short* xn  = (unsigned short*)d_out;                 // bf16 [4096,2048]
  unsigned short* ctx = xn;                                     // bf16 [4096,2048]
  unsigned short* qb  = (unsigned short*)((char*)d_out + 16777216); // [B,H,S,hd]
  unsigned short* hn  = qb;                                     // reuse after attn

  const bool bigws = ws_size >= (size_t)167772160;              // >= 160 MiB
  unsigned short* w2t = bigws ? (unsigned short*)(ws + 134217728) : Wt;

  const dim3 b256(256);

  prep_k<<<37120, b256, 0, stream>>>(x, ln1g, ln1b, xn, kc, kf, out_k,
                                     vc, vft, out_v, mask, mflags,
                                     q_w, k_w, v_w, o_w, Wt);

  gemm8p<0, 0><<<384, dim3(512), 0, stream>>>(
      xn, Wt, q_b, k_b, v_b, out_k, qb, out_v, kf, vft, 6144, 2048);

  attn6<<<dim3(16, 32), b256, 0, stream>>>(qb, kf, vft, mask, mflags, ctx);

  gemm8n<1, 1><<<256, dim3(512), 0, stream>>>(
      ctx, Wt + (size_t)6144 * 2048, o_b, x, x1, 2048, 2048);

  prep2_k<<<bigws ? 36864 : 20480, b256, 0, stream>>>(
      x1, ln2g, ln2b, hn, w1, Wt, w2, w2t);

  gemm8p<2, 2><<<512, dim3(512), 0, stream>>>(
      hn, Wt, b1, nullptr, nullptr, nullptr, mid, nullptr, nullptr, nullptr,
      8192, 2048);

  if (!bigws) wconvT<<<dim3(256, 64), b256, 0, stream>>>(w2, Wt, 8192, 2048);

  gemm8n<3, 1><<<256, dim3(512), 0, stream>>>(
      mid, w2t, b2, x1, out_x, 2048, 8192);
}

// Round 16
// 790.958 us; speedup vs baseline: 1.5672x; 1.0073x over previous
//
#include <hip/hip_runtime.h>
#include <hip/hip_bf16.h>

// ---------------------------------------------------------------------------
// KVCacheTransformerLayer on MI355X (gfx950). bf16 MFMA compute, fp32 spine.
// S=2048, PAST=2048, T=4096, B=2, H=16, hd=128, D=2048, DFF=8192, M=S*B=4096.
// ---------------------------------------------------------------------------

typedef __bf16 bf16x8 __attribute__((ext_vector_type(8)));
typedef float f32x4 __attribute__((ext_vector_type(4)));
typedef float f32x16 __attribute__((ext_vector_type(16)));
typedef unsigned int u32;

__device__ __forceinline__ unsigned short f2bf(float f) {
  union { float f; unsigned u; } v; v.f = f;
  return (unsigned short)((v.u + 0x7FFFu + ((v.u >> 16) & 1u)) >> 16);
}

__device__ __forceinline__ float fexp2(float x) {
#if __has_builtin(__builtin_amdgcn_exp2f)
  return __builtin_amdgcn_exp2f(x);
#else
  float r;
  asm volatile("v_exp_f32 %0, %1\ns_nop 0" : "=v"(r) : "v"(x));
  return r;
#endif
}

// fast exact-enough GELU: x*e/(e+1), e = exp(2u). Max dev ~3e-4.
__device__ __forceinline__ float fast_gelu(float x) {
  const float u = 0.7978845608028654f * fmaf(0.044715f * x * x, x, x);
  const float e = fexp2(fminf(u * 2.885390081777927f, 126.f));
  float rcp;
  asm("v_rcp_f32 %0, %1" : "=v"(rcp) : "v"(e + 1.f));
  return x * e * rcp;
}

// async global->LDS, 16B per lane; LDS dest = wave-uniform base + lane*16
__device__ __forceinline__ void gl16(const void* g, void* l) {
  __builtin_amdgcn_global_load_lds((__attribute__((address_space(1))) void*)g,
                                   (__attribute__((address_space(3))) void*)l,
                                   16, 0, 0);
}

// ------------- weight convert fp32 [K,N] -> bf16 transposed [N,K] -----------
__global__ __launch_bounds__(256) void wconvT(const float* __restrict__ W,
                                              unsigned short* __restrict__ Wt,
                                              int K, int N) {
  __shared__ float tl[32][33];
  const int k0 = blockIdx.x * 32, n0 = blockIdx.y * 32;
  const int x = threadIdx.x & 31, y = threadIdx.x >> 5;
  for (int i = 0; i < 4; ++i)
    tl[y + i * 8][x] = W[(size_t)(k0 + y + i * 8) * N + n0 + x];
  __syncthreads();
  for (int i = 0; i < 4; ++i)
    Wt[(size_t)(n0 + y + i * 8) * K + k0 + x] = f2bf(tl[x][y + i * 8]);
}

// ---- fused prep: LN1 | kpack | vtrans | mask0 | wconvT4 in ONE dispatch ----
__global__ __launch_bounds__(256) void prep_k(
    const float* __restrict__ x, const float* __restrict__ ln1g,
    const float* __restrict__ ln1b, unsigned short* __restrict__ xn,
    const float* __restrict__ kc, unsigned short* __restrict__ kf,
    float* __restrict__ out_k,
    const float* __restrict__ vc, unsigned short* __restrict__ vft,
    float* __restrict__ out_v,
    const float* __restrict__ mask, u32* __restrict__ mflags,
    const float* __restrict__ q_w, const float* __restrict__ k_w,
    const float* __restrict__ v_w, const float* __restrict__ o_w,
    unsigned short* __restrict__ Wt) {
  __shared__ float tl[32][33];
  __shared__ float red[8];
  const int blk = blockIdx.x;
  const int tid = threadIdx.x;

  if (blk < 4096) {
    const int row = blk;
    const float4* xr = (const float4*)(x + (size_t)row * 2048);
    const float4 xa = xr[tid], xb = xr[tid + 256];
    float s = xa.x + xa.y + xa.z + xa.w + xb.x + xb.y + xb.z + xb.w;
    float q = xa.x * xa.x + xa.y * xa.y + xa.z * xa.z + xa.w * xa.w +
              xb.x * xb.x + xb.y * xb.y + xb.z * xb.z + xb.w * xb.w;
    for (int off = 32; off; off >>= 1) {
      s += __shfl_xor(s, off);
      q += __shfl_xor(q, off);
    }
    const int wv = tid >> 6, ln = tid & 63;
    if (ln == 0) { red[wv] = s; red[4 + wv] = q; }
    __syncthreads();
    s = red[0] + red[1] + red[2] + red[3];
    q = red[4] + red[5] + red[6] + red[7];
    const float mean = s * (1.f / 2048.f);
    const float rstd = rsqrtf(q * (1.f / 2048.f) - mean * mean + 1e-5f);
    const float4 g0 = ((const float4*)ln1g)[tid], g1 = ((const float4*)ln1g)[tid + 256];
    const float4 b0 = ((const float4*)ln1b)[tid], b1 = ((const float4*)ln1b)[tid + 256];
    ushort4 o0, o1;
    o0.x = f2bf((xa.x - mean) * rstd * g0.x + b0.x);
    o0.y = f2bf((xa.y - mean) * rstd * g0.y + b0.y);
    o0.z = f2bf((xa.z - mean) * rstd * g0.z + b0.z);
    o0.w = f2bf((xa.w - mean) * rstd * g0.w + b0.w);
    o1.x = f2bf((xb.x - mean) * rstd * g1.x + b1.x);
    o1.y = f2bf((xb.y - mean) * rstd * g1.y + b1.y);
    o1.z = f2bf((xb.z - mean) * rstd * g1.z + b1.z);
    o1.w = f2bf((xb.w - mean) * rstd * g1.w + b1.w);
    ((ushort4*)(xn + (size_t)row * 2048))[tid] = o0;
    ((ushort4*)(xn + (size_t)row * 2048))[tid + 256] = o1;
  } else if (blk < 12288) {
    const size_t e = ((size_t)(blk - 4096) * 256 + tid) * 4;
    const int r = (int)(e >> 11), c = (int)(e & 2047);
    const int t = r >> 1, b = r & 1, h = c >> 7, d = c & 127;
    const float4 v = *(const float4*)(kc + e);
    ushort4 o;
    o.x = f2bf(v.x); o.y = f2bf(v.y); o.z = f2bf(v.z); o.w = f2bf(v.w);
    *(ushort4*)(kf + ((size_t)((b * 16 + h) * 4096 + t)) * 128 + d) = o;
    *(float4*)(out_k + (size_t)r * 2048 + c) = v;
  } else if (blk < 20480) {
    const int i = blk - 12288;
    const int t0 = (i & 63) * 32, d0 = ((i >> 6) & 3) * 32, bh = i >> 8;
    const int b = bh >> 4, h = bh & 15;
    const int xx = tid & 31, yy = tid >> 5;
    for (int ii = 0; ii < 4; ++ii) {
      const int t = t0 + yy + ii * 8, d = d0 + xx;
      const float v = vc[((size_t)(t * 2 + b) * 16 + h) * 128 + d];
      tl[yy + ii * 8][xx] = v;
      out_v[((size_t)(t * 2 + b) * 16 + h) * 128 + d] = v;
    }
    __syncthreads();
    for (int ii = 0; ii < 4; ++ii) {
      const int d = d0 + yy + ii * 8, t = t0 + xx;
      vft[((size_t)bh * 128 + d) * 4096 + t] = f2bf(tl[xx][yy + ii * 8]);
    }
  } else if (blk < 20736) {
    const int mb = blk - 20480;
    const float4* p = (const float4*)mask + (size_t)mb * 8192 + tid;
    int nz = 0;
#pragma unroll
    for (int ii = 0; ii < 32; ++ii) {
      const float4 v = p[ii * 256];
      nz |= (v.x != 0.f) | (v.y != 0.f) | (v.z != 0.f) | (v.w != 0.f);
    }
    const int r = __syncthreads_or(nz);
    if (tid == 0) mflags[mb] = (u32)r;
  } else {
    const int i = blk - 20736;
    const int k0 = (i & 63) * 32, n0 = ((i >> 6) & 63) * 32, z = i >> 12;
    const float* W = z == 0 ? q_w : (z == 1 ? k_w : (z == 2 ? v_w : o_w));
    unsigned short* dst = Wt + (size_t)z * 2048 * 2048;
    const int xx = tid & 31, yy = tid >> 5;
    for (int ii = 0; ii < 4; ++ii)
      tl[yy + ii * 8][xx] = W[(size_t)(k0 + yy + ii * 8) * 2048 + n0 + xx];
    __syncthreads();
    for (int ii = 0; ii < 4; ++ii)
      dst[(size_t)(n0 + yy + ii * 8) * 2048 + k0 + xx] = f2bf(tl[xx][yy + ii * 8]);
  }
}

// ---- fused prep2: LN2 | wconvT(w1) | optional wconvT(w2) in ONE dispatch ---
__global__ __launch_bounds__(256) void prep2_k(
    const float* __restrict__ x1, const float* __restrict__ ln2g,
    const float* __restrict__ ln2b, unsigned short* __restrict__ hn,
    const float* __restrict__ w1, unsigned short* __restrict__ w1t,
    const float* __restrict__ w2, unsigned short* __restrict__ w2t) {
  __shared__ float tl[32][33];
  __shared__ float red[8];
  const int blk = blockIdx.x;
  const int tid = threadIdx.x;

  if (blk < 4096) {
    const int row = blk;
    const float4* xr = (const float4*)(x1 + (size_t)row * 2048);
    const float4 xa = xr[tid], xb = xr[tid + 256];
    float s = xa.x + xa.y + xa.z + xa.w + xb.x + xb.y + xb.z + xb.w;
    float q = xa.x * xa.x + xa.y * xa.y + xa.z * xa.z + xa.w * xa.w +
              xb.x * xb.x + xb.y * xb.y + xb.z * xb.z + xb.w * xb.w;
    for (int off = 32; off; off >>= 1) {
      s += __shfl_xor(s, off);
      q += __shfl_xor(q, off);
    }
    const int wv = tid >> 6, ln = tid & 63;
    if (ln == 0) { red[wv] = s; red[4 + wv] = q; }
    __syncthreads();
    s = red[0] + red[1] + red[2] + red[3];
    q = red[4] + red[5] + red[6] + red[7];
    const float mean = s * (1.f / 2048.f);
    const float rstd = rsqrtf(q * (1.f / 2048.f) - mean * mean + 1e-5f);
    const float4 g0 = ((const float4*)ln2g)[tid], g1 = ((const float4*)ln2g)[tid + 256];
    const float4 b0 = ((const float4*)ln2b)[tid], b1 = ((const float4*)ln2b)[tid + 256];
    ushort4 o0, o1;
    o0.x = f2bf((xa.x - mean) * rstd * g0.x + b0.x);
    o0.y = f2bf((xa.y - mean) * rstd * g0.y + b0.y);
    o0.z = f2bf((xa.z - mean) * rstd * g0.z + b0.z);
    o0.w = f2bf((xa.w - mean) * rstd * g0.w + b0.w);
    o1.x = f2bf((xb.x - mean) * rstd * g1.x + b1.x);
    o1.y = f2bf((xb.y - mean) * rstd * g1.y + b1.y);
    o1.z = f2bf((xb.z - mean) * rstd * g1.z + b1.z);
    o1.w = f2bf((xb.w - mean) * rstd * g1.w + b1.w);
    ((ushort4*)(hn + (size_t)row * 2048))[tid] = o0;
    ((ushort4*)(hn + (size_t)row * 2048))[tid + 256] = o1;
  } else if (blk < 20480) {
    const int i = blk - 4096;
    const int k0 = (i & 63) * 32, n0 = (i >> 6) * 32;
    const int xx = tid & 31, yy = tid >> 5;
    for (int ii = 0; ii < 4; ++ii)
      tl[yy + ii * 8][xx] = w1[(size_t)(k0 + yy + ii * 8) * 8192 + n0 + xx];
    __syncthreads();
    for (int ii = 0; ii < 4; ++ii)
      w1t[(size_t)(n0 + yy + ii * 8) * 2048 + k0 + xx] = f2bf(tl[xx][yy + ii * 8]);
  } else {
    const int i = blk - 20480;
    const int k0 = (i & 255) * 32, n0 = (i >> 8) * 32;
    const int xx = tid & 31, yy = tid >> 5;
    for (int ii = 0; ii < 4; ++ii)
      tl[yy + ii * 8][xx] = w2[(size_t)(k0 + yy + ii * 8) * 2048 + n0 + xx];
    __syncthreads();
    for (int ii = 0; ii < 4; ++ii)
      w2t[(size_t)(n0 + yy + ii * 8) * 8192 + k0 + xx] = f2bf(tl[xx][yy + ii * 8]);
  }
}

// --------- 256x256 8-phase GEMM (T2+T3+T4+T5), BK=64, 8 waves (2x4) ---------
// EPI: 0 = QKV packed outputs (LDS-gathered bf16 + direct fp32),
//      2 = GELU bf16 out via LDS-transposed epilogue.
template <int TAG, int EPI>
__global__ __launch_bounds__(512, 2) void gemm8p(
    const unsigned short* __restrict__ A, const unsigned short* __restrict__ Bt,
    const float* __restrict__ bias, const float* __restrict__ bias2,
    const float* __restrict__ bias3,
    float* __restrict__ Cf, unsigned short* __restrict__ Cb,
    float* __restrict__ of2, unsigned short* __restrict__ pb2,
    unsigned short* __restrict__ pb3, int N, int K) {
  // flat 128 KB: sA[bb] @ bb*32768, sB[bb] @ 65536 + bb*32768
  __shared__ __attribute__((aligned(16))) char smem[131072];
  const int tid = threadIdx.x;
  const int wv = tid >> 6, ln = tid & 63;
  const int wm = wv >> 2, wn = wv & 3;         // 2 x 4 waves
  const int nwg = gridDim.x;
  const int bid = blockIdx.x;
  const int wk = (bid & 7) * (nwg >> 3) + (bid >> 3);
  const int nmt = 16;                          // M/256
  const int m0 = (wk & (nmt - 1)) * 256, n0 = (wk / nmt) * 256;
  const int NT = K >> 6, NI = NT >> 1;

  f32x4 acc[8][4] = {};
  bf16x8 af[4][2], bfr[2][2];

  auto ST = [&](int t, int which, int bb) {
    if (t >= NT) return;
    const unsigned short* G = (which < 2) ? A : Bt;
    const int base0 = ((which < 2) ? m0 : n0) + (which & 1) * 128;
    char* dst = smem + ((which < 2) ? bb * 32768 : 65536 + bb * 32768) +
                (which & 1) * 16384;
    const size_t kb = (size_t)t * 64;
#pragma unroll
    for (int c = 0; c < 2; ++c) {
      const int o = tid * 16 + c * 8192;
      const int row = o >> 7;
      const int cb = (o & 127) ^ ((row & 7) << 4);
      gl16((const char*)G + ((size_t)(base0 + row) * K + kb) * 2 + cb, dst + o);
    }
  };
  auto LDA = [&](int bb, int mh) {
    const char* base = smem + bb * 32768;
#pragma unroll
    for (int i = 0; i < 4; ++i) {
      const int r = wm * 128 + mh * 64 + i * 16 + (ln & 15);
#pragma unroll
      for (int kk = 0; kk < 2; ++kk) {
        int aa = (r << 7) + ((ln >> 4) << 4) + kk * 64;
        aa ^= (r & 7) << 4;
        af[i][kk] = *(const bf16x8*)(base + aa);
      }
    }
  };
  auto LDB = [&](int bb, int nh) {
    const char* base = smem + 65536 + bb * 32768;
#pragma unroll
    for (int j = 0; j < 2; ++j) {
      const int r = wn * 64 + nh * 32 + j * 16 + (ln & 15);
#pragma unroll
      for (int kk = 0; kk < 2; ++kk) {
        int aa = (r << 7) + ((ln >> 4) << 4) + kk * 64;
        aa ^= (r & 7) << 4;
        bfr[j][kk] = *(const bf16x8*)(base + aa);
      }
    }
  };
  auto MM = [&](int mh, int nh) {
    __builtin_amdgcn_s_setprio(1);
#pragma unroll
    for (int i = 0; i < 4; ++i)
#pragma unroll
      for (int j = 0; j < 2; ++j)
#pragma unroll
        for (int kk = 0; kk < 2; ++kk)
          acc[mh * 4 + i][nh * 2 + j] = __builtin_amdgcn_mfma_f32_16x16x32_bf16(
              af[i][kk], bfr[j][kk], acc[mh * 4 + i][nh * 2 + j], 0, 0, 0);
    __builtin_amdgcn_s_setprio(0);
  };
#define BAR() __builtin_amdgcn_s_barrier()
#define VM2() asm volatile("s_waitcnt vmcnt(2)" ::: "memory")
#define VM0() asm volatile("s_waitcnt vmcnt(0)" ::: "memory")

  ST(0, 0, 0); ST(0, 1, 0); ST(0, 2, 0); ST(0, 3, 0); ST(1, 0, 1);
  VM2();
  BAR();

#pragma unroll 1
  for (int it = 0; it < NI; ++it) {
    const int t1 = 2 * it + 1, t2 = 2 * it + 2, t3 = 2 * it + 3;
    const bool lastit = (it == NI - 1);
    LDA(0, 0); LDB(0, 0); ST(t1, 1, 1); BAR(); MM(0, 0); BAR();   // P1
    LDB(0, 1);            ST(t1, 2, 1); BAR(); MM(0, 1); BAR();   // P2
    LDA(0, 1);            ST(t1, 3, 1); BAR(); MM(1, 1); BAR();   // P3
    LDB(0, 0);            ST(t2, 0, 0); BAR(); MM(1, 0);          // P4
    if (lastit) VM0(); else VM2();
    BAR();
    LDA(1, 0); LDB(1, 0); ST(t2, 1, 0); BAR(); MM(0, 0); BAR();   // P5
    LDB(1, 1);            ST(t2, 2, 0); BAR(); MM(0, 1); BAR();   // P6
    LDA(1, 1);            ST(t2, 3, 0); BAR(); MM(1, 1); BAR();   // P7
    LDB(1, 0);            ST(t3, 0, 1); BAR(); MM(1, 0);          // P8
    if (!lastit) VM2();
    BAR();
  }
#undef BAR
#undef VM2
#undef VM0

  const int lr = (ln >> 4) << 2, lc = ln & 15;
  if (EPI == 0) {
    // QKV packed. seg: 0=Q(bf16 qb), 1=K(bf16 kf + fp32 out_k),
    // 2=V(bf16 vft transposed + fp32 out_v). Block in one 2048-col segment.
    const int seg = n0 >> 11;
    const float* bp = seg == 0 ? bias : (seg == 1 ? bias2 : bias3);
    // (1) direct fp32 writes (affine rows, coalesced along nn)
    if (seg == 1 || seg == 2) {
#pragma unroll
      for (int f = 0; f < 8; ++f) {
#pragma unroll
        for (int j = 0; j < 4; ++j) {
          const int nn = (n0 & 2047) + wn * 64 + j * 16 + lc;
          const float bv = bp[nn];
#pragma unroll
          for (int r = 0; r < 4; ++r) {
            const int m = m0 + wm * 128 + f * 16 + lr + r;
            const float v = acc[f][j][r] + bv;
            float* dstf = (seg == 1) ? Cf : of2;
            dstf[(size_t)(4096 + m) * 2048 + nn] = v;
          }
        }
      }
    }
    // (2) stage bias-added bf16 C-tile into LDS [ml 256][nl 256] (swizzled)
#pragma unroll
    for (int f = 0; f < 8; ++f) {
#pragma unroll
      for (int j = 0; j < 4; ++j) {
        const int nl = wn * 64 + j * 16 + lc;       // 0..255
        const float bv = bp[(n0 & 2047) + nl];
#pragma unroll
        for (int r = 0; r < 4; ++r) {
          const int ml = wm * 128 + f * 16 + lr + r;  // 0..255
          *(unsigned short*)(smem + ml * 512 + ((nl * 2) ^ ((ml & 7) << 4))) =
              f2bf(acc[f][j][r] + bv);
        }
      }
    }
    __syncthreads();
    const int h0 = (n0 & 2047) >> 7;                 // first head of tile
    if (seg == 0 || seg == 1) {
      const int ml = tid >> 1, hl = tid & 1;
      const int m = m0 + ml, s = m >> 1, b = m & 1, h = h0 + hl;
      char* drow = (seg == 0)
          ? (char*)Cb + ((size_t)(b * 16 + h) * 2048 + s) * 256
          : (char*)pb2 + ((size_t)(b * 16 + h) * 4096 + 2048 + s) * 256;
#pragma unroll
      for (int c = 0; c < 16; ++c) {
        const int4 val = *(const int4*)(
            smem + ml * 512 + ((hl * 256 + c * 16) ^ ((ml & 7) << 4)));
        *(int4*)(drow + c * 16) = val;
      }
    } else {
      const int hl = tid >> 8, d = (tid >> 1) & 127, b = tid & 1;
      const int nl2 = (hl * 128 + d) * 2;
      char* drow = (char*)pb3 +
          ((size_t)((b * 16 + h0 + hl) * 128 + d) * 4096 + 2048 + (m0 >> 1)) * 2;
#pragma unroll
      for (int sc = 0; sc < 16; ++sc) {
        union { unsigned short u[8]; int4 v; } t8;
#pragma unroll
        for (int si = 0; si < 8; ++si) {
          const int ml = (sc * 8 + si) * 2 + b;
          t8.u[si] = *(const unsigned short*)(
              smem + ml * 512 + (nl2 ^ ((ml & 7) << 4)));
        }
        *(int4*)(drow + sc * 16) = t8.v;
      }
    }
  } else {
    // EPI==2: fast-GELU -> per-wave LDS tile -> coalesced bf16x8 stores
    char* wbase = smem + wv * 16384;
#pragma unroll
    for (int f = 0; f < 8; ++f) {
#pragma unroll
      for (int j = 0; j < 4; ++j) {
        const int nl = j * 16 + lc;
        const float bv = bias[n0 + wn * 64 + nl];
#pragma unroll
        for (int r = 0; r < 4; ++r) {
          const int ml = f * 16 + lr + r;
          const float v = fast_gelu(acc[f][j][r] + bv);
          *(unsigned short*)(wbase + ml * 128 + ((nl * 2) ^ ((ml & 7) << 4))) =
              f2bf(v);
        }
      }
    }
    __syncthreads();
#pragma unroll
    for (int p = 0; p < 16; ++p) {
      const int row = p * 16 + (tid >> 5);
      const int nn = (tid & 31) * 8;
      const int wvv = (row >> 7) * 4 + (nn >> 6);
      const char* rb = smem + wvv * 16384;
      const int ml = row & 127, nl = nn & 63;
      const int4 val = *(const int4*)(rb + ml * 128 + ((nl * 2) ^ ((ml & 7) << 4)));
      *(int4*)((char*)Cb + ((size_t)(m0 + row) * N + n0 + nn) * 2) = val;
    }
  }
}

// ---- 128x256 8-phase GEMM, BK=64, 8 waves (2x4, 64x64 each), 96 KB LDS -----
// EPI: 1 = fp32 out + residual. (O-proj / FFN2)
template <int TAG, int EPI>
__global__ __launch_bounds__(512, 2) void gemm8n(
    const unsigned short* __restrict__ A, const unsigned short* __restrict__ Bt,
    const float* __restrict__ bias, const float* __restrict__ Rsd,
    float* __restrict__ Cf, int N, int K) {
  __shared__ unsigned short sA[2][128 * 64];   // 32 KB
  __shared__ unsigned short sB[2][256 * 64];   // 64 KB
  const int tid = threadIdx.x;
  const int wv = tid >> 6, ln = tid & 63;
  const int wm = wv >> 2, wn = wv & 3;
  const int nwg = gridDim.x;
  const int bid = blockIdx.x;
  const int wk = (bid & 7) * (nwg >> 3) + (bid >> 3);
  const int m0 = (wk & 31) * 128, n0 = (wk >> 5) * 256;
  const int NT = K >> 6;

  f32x4 acc[4][4] = {};
  bf16x8 af[2][2], bfr[2][2];

  auto ST = [&](int t, int which, int bb) {
    if (t >= NT) return;
    const unsigned short* G = (which == 0) ? A : Bt;
    const int base0 = (which == 0) ? m0 : (which == 1 ? n0 : n0 + 128);
    char* dst = (which == 0) ? (char*)&sA[bb][0]
                             : (char*)&sB[bb][0] + (which - 1) * 16384;
    const size_t kb = (size_t)t * 64;
#pragma unroll
    for (int c = 0; c < 2; ++c) {
      const int o = tid * 16 + c * 8192;
      const int row = o >> 7;
      const int cb = (o & 127) ^ ((row & 7) << 4);
      gl16((const char*)G + ((size_t)(base0 + row) * K + kb) * 2 + cb, dst + o);
    }
  };
  auto LDA = [&](int bb, int mh) {
    const char* base = (const char*)&sA[bb][0];
#pragma unroll
    for (int i = 0; i < 2; ++i) {
      const int r = wm * 64 + mh * 32 + i * 16 + (ln & 15);
#pragma unroll
      for (int kk = 0; kk < 2; ++kk) {
        int aa = (r << 7) + ((ln >> 4) << 4) + kk * 64;
        aa ^= (r & 7) << 4;
        af[i][kk] = *(const bf16x8*)(base + aa);
      }
    }
  };
  auto LDB = [&](int bb, int nh) {
    const char* base = (const char*)&sB[bb][0];
#pragma unroll
    for (int j = 0; j < 2; ++j) {
      const int r = wn * 64 + nh * 32 + j * 16 + (ln & 15);
#pragma unroll
      for (int kk = 0; kk < 2; ++kk) {
        int aa = (r << 7) + ((ln >> 4) << 4) + kk * 64;
        aa ^= (r & 7) << 4;
        bfr[j][kk] = *(const bf16x8*)(base + aa);
      }
    }
  };
  auto MM = [&](int mh, int nh) {
    __builtin_amdgcn_s_setprio(1);
#pragma unroll
    for (int i = 0; i < 2; ++i)
#pragma unroll
      for (int j = 0; j < 2; ++j)
#pragma unroll
        for (int kk = 0; kk < 2; ++kk)
          acc[mh * 2 + i][nh * 2 + j] = __builtin_amdgcn_mfma_f32_16x16x32_bf16(
              af[i][kk], bfr[j][kk], acc[mh * 2 + i][nh * 2 + j], 0, 0, 0);
    __builtin_amdgcn_s_setprio(0);
  };
#define BAR() __builtin_amdgcn_s_barrier()
#define VM2() asm volatile("s_waitcnt vmcnt(2)" ::: "memory")
#define VM0() asm volatile("s_waitcnt vmcnt(0)" ::: "memory")

  ST(0, 0, 0); ST(0, 1, 0); ST(0, 2, 0); ST(1, 0, 1);
  VM2();
  BAR();

#pragma unroll 1
  for (int t = 0; t < NT; ++t) {
    const int cur = t & 1;
    LDA(cur, 0); LDB(cur, 0); ST(t + 1, 1, cur ^ 1); BAR(); MM(0, 0); BAR();
    LDB(cur, 1); ST(t + 1, 2, cur ^ 1); BAR(); MM(0, 1); BAR();
    LDA(cur, 1); BAR(); MM(1, 1); BAR();
    LDB(cur, 0); ST(t + 2, 0, cur); BAR(); MM(1, 0);
    if (t >= NT - 2) VM0(); else VM2();
    BAR();
  }
#undef BAR
#undef VM2
#undef VM0

  const int lr = (ln >> 4) << 2, lc = ln & 15;
#pragma unroll
  for (int i = 0; i < 4; ++i) {
#pragma unroll
    for (int j = 0; j < 4; ++j) {
      const int n = n0 + wn * 64 + j * 16 + lc;
      const float bv = bias[n];
#pragma unroll
      for (int r = 0; r < 4; ++r) {
        const int m = m0 + wm * 64 + i * 16 + lr + r;
        const float v = acc[i][j][r] + bv + Rsd[(size_t)m * N + n];
        Cf[(size_t)m * N + n] = v;
      }
    }
  }
}

// ------------- flash attention, 4 waves x 32 q-rows, KVBLK=64 ---------------
// attn6 + XCD-grouped flat grid (512): all 16 q-blocks of one bh map to the
// same XCD so the head's K/V stream stays in that XCD's private L2.
__global__ __launch_bounds__(256, 2) void attn6(
    const unsigned short* __restrict__ Q,   // [B*H, S, 128] bf16
    const unsigned short* __restrict__ Kf,  // [B*H, T, 128] bf16
    const unsigned short* __restrict__ Vt,  // [B*H, 128, T] bf16
    const float* __restrict__ mask,         // [S, T] fp32
    const u32* __restrict__ flags,          // 256 zero-detect flags
    unsigned short* __restrict__ ctx) {     // [(s,b), (h,d)] bf16
  __shared__ __attribute__((aligned(16))) char smem[65536];
  const int tid = threadIdx.x;
  const int wv = tid >> 6;
  const int ln = tid & 63;
  const int q = ln & 31;
  const int hi = ln >> 5;
  const int sw = (q & 7) << 4;
  // XCD-grouped swizzle: 512 blocks, 8 XCDs, 64 blocks/XCD = 4 bh * 16 qblk
  const int wk = (blockIdx.x & 7) * 64 + (blockIdx.x >> 3);
  const int bh = wk >> 4;
  const int s0w = (wk & 15) * 128 + wv * 32;

  const int mnz = __syncthreads_or((int)flags[tid]);

  bf16x8 qreg[8];
  {
    const char* qsrc = (const char*)Q +
        ((size_t)bh * 2048 + s0w + q) * 256 + (hi << 4);
#pragma unroll
    for (int kk = 0; kk < 8; ++kk) qreg[kk] = *(const bf16x8*)(qsrc + kk * 32);
  }

  const char* kp[8];
  const char* vp[4];
#pragma unroll
  for (int kk = 0; kk < 8; ++kk)
    kp[kk] = smem + (q << 8) + (((kk << 5) + (hi << 4)) ^ sw);
#pragma unroll
  for (int kk = 0; kk < 4; ++kk)
    vp[kk] = smem + 32768 + (q << 7) + (((kk << 5) + (hi << 4)) ^ sw);

  const char* Kg;
  const char* Vg;
  {
    const int oo = tid * 16;
    const int kr = oo >> 8, kc = oo & 255;
    Kg = (const char*)Kf + (size_t)bh * 4096 * 256 + (size_t)kr * 256 +
         (kc ^ ((kr & 7) << 4));
    const int vr = oo >> 7, vc = oo & 127;
    Vg = (const char*)Vt + (size_t)bh * 128 * 8192 + (size_t)vr * 8192 +
         (vc ^ ((vr & 7) << 4));
  }
  char* kdst = smem + tid * 16;
  char* vdst = smem + 32768 + tid * 16;

#define STG(BUF)                                               \
  do {                                                         \
    _Pragma("unroll") for (int is = 0; is < 4; ++is) {         \
      gl16(Kg + is * 4096, kdst + (BUF) + is * 4096);          \
      gl16(Vg + (size_t)is * 262144, vdst + (BUF) + is * 4096);\
    }                                                          \
    Kg += 16384; Vg += 128;                                    \
  } while (0)
#define BARR() __builtin_amdgcn_s_barrier()
#define VMW8() asm volatile("s_waitcnt vmcnt(8)" ::: "memory")
#define VMW0() asm volatile("s_waitcnt vmcnt(0)" ::: "memory")

  f32x16 acc[4] = {};
  float m = -1e30f, l = 0.f;
  const float KLOG = 0.127517445f;   // (1/sqrt(128)) * log2(e)

  auto tile = [&](int BUF, int it) {
    f32x16 sc0, sc1;
    {
      f32x16 za = {}, zb = {}, zc = {}, zd = {};
      __builtin_amdgcn_s_setprio(1);
#pragma unroll
      for (int kk = 0; kk < 4; ++kk) {
        za = __builtin_amdgcn_mfma_f32_32x32x16_bf16(
            *(const bf16x8*)(kp[kk] + BUF), qreg[kk], za, 0, 0, 0);
        zb = __builtin_amdgcn_mfma_f32_32x32x16_bf16(
            *(const bf16x8*)(kp[kk + 4] + BUF), qreg[kk + 4], zb, 0, 0, 0);
        zc = __builtin_amdgcn_mfma_f32_32x32x16_bf16(
            *(const bf16x8*)(kp[kk] + BUF + 8192), qreg[kk], zc, 0, 0, 0);
        zd = __builtin_amdgcn_mfma_f32_32x32x16_bf16(
            *(const bf16x8*)(kp[kk + 4] + BUF + 8192), qreg[kk + 4], zd, 0, 0, 0);
      }
      __builtin_amdgcn_s_setprio(0);
      sc0 = za + zb;
      sc1 = zc + zd;
    }

    if (mnz) {
      const float rs = 11.313708498984761f;  // sqrt(128)
#pragma unroll
      for (int r = 0; r < 16; ++r) {
        const int tt = it * 64 + ((r & 3) + ((r >> 2) << 3) + (hi << 2));
        sc0[r] = fmaf(mask[(size_t)(s0w + q) * 4096 + tt], rs, sc0[r]);
        sc1[r] = fmaf(mask[(size_t)(s0w + q) * 4096 + tt + 32], rs, sc1[r]);
      }
    }

    float pmax = sc0[0];
#pragma unroll
    for (int r = 1; r < 16; ++r) pmax = fmaxf(pmax, sc0[r]);
#pragma unroll
    for (int r = 0; r < 16; ++r) pmax = fmaxf(pmax, sc1[r]);
    pmax = fmaxf(pmax, __shfl_xor(pmax, 32));
    if (__any(pmax > m + 90.5f)) {
      const float mn = fmaxf(m, pmax);
      const float corr = fexp2((m - mn) * KLOG);
      m = mn; l *= corr;
#pragma unroll
      for (int d4 = 0; d4 < 4; ++d4)
#pragma unroll
        for (int e = 0; e < 16; ++e) acc[d4][e] *= corr;
    }
    const float mk = m * KLOG;
    float rsum = 0.f;
#pragma unroll
    for (int r = 0; r < 16; ++r) {
      const float e = fexp2(fmaf(sc0[r], KLOG, -mk));
      sc0[r] = e;
      rsum += e;
    }
#pragma unroll
    for (int r = 0; r < 16; ++r) {
      const float e = fexp2(fmaf(sc1[r], KLOG, -mk));
      sc1[r] = e;
      rsum += e;
    }
    rsum += __shfl_xor(rsum, 32);
    l += rsum;

    bf16x8 pw[4];
#pragma unroll
    for (int kk = 0; kk < 4; ++kk) {
      const int rb = (kk & 1) * 8;
      u32 w0, w1, w2, w3;
      if (kk < 2) {
        asm("v_cvt_pk_bf16_f32 %0, %1, %2" : "=v"(w0) : "v"(sc0[rb + 0]), "v"(sc0[rb + 1]));
        asm("v_cvt_pk_bf16_f32 %0, %1, %2" : "=v"(w1) : "v"(sc0[rb + 2]), "v"(sc0[rb + 3]));
        asm("v_cvt_pk_bf16_f32 %0, %1, %2" : "=v"(w2) : "v"(sc0[rb + 4]), "v"(sc0[rb + 5]));
        asm("v_cvt_pk_bf16_f32 %0, %1, %2" : "=v"(w3) : "v"(sc0[rb + 6]), "v"(sc0[rb + 7]));
      } else {
        asm("v_cvt_pk_bf16_f32 %0, %1, %2" : "=v"(w0) : "v"(sc1[rb + 0]), "v"(sc1[rb + 1]));
        asm("v_cvt_pk_bf16_f32 %0, %1, %2" : "=v"(w1) : "v"(sc1[rb + 2]), "v"(sc1[rb + 3]));
        asm("v_cvt_pk_bf16_f32 %0, %1, %2" : "=v"(w2) : "v"(sc1[rb + 4]), "v"(sc1[rb + 5]));
        asm("v_cvt_pk_bf16_f32 %0, %1, %2" : "=v"(w3) : "v"(sc1[rb + 6]), "v"(sc1[rb + 7]));
      }
      asm("v_permlane32_swap_b32 %0, %1" : "+v"(w0), "+v"(w2));
      asm("v_permlane32_swap_b32 %0, %1" : "+v"(w1), "+v"(w3));
      union { u32 u[4]; bf16x8 b; } pk;
      pk.u[0] = w0; pk.u[1] = w1; pk.u[2] = w2; pk.u[3] = w3;
      pw[kk] = pk.b;
    }

#pragma unroll
    for (int d4 = 0; d4 < 4; ++d4) {
      __builtin_amdgcn_s_setprio(1);
#pragma unroll
      for (int kk = 0; kk < 4; ++kk)
        acc[d4] = __builtin_amdgcn_mfma_f32_32x32x16_bf16(
            *(const bf16x8*)(vp[kk] + BUF + d4 * 4096), pw[kk], acc[d4], 0, 0, 0);
      __builtin_amdgcn_s_setprio(0);
    }
  };

  STG(0);
  STG(16384);
#pragma unroll 1
  for (int it2 = 0; it2 < 31; ++it2) {
    VMW8(); BARR();
    tile(0, 2 * it2);
    BARR();
    STG(0);
    VMW8(); BARR();
    tile(16384, 2 * it2 + 1);
    BARR();
    STG(16384);
  }
  VMW8(); BARR();
  tile(0, 62);
  BARR();
  VMW0(); BARR();
  tile(16384, 63);
#undef STG
#undef BARR
#undef VMW8
#undef VMW0

  const float inv = 1.f / l;
  const int b = bh >> 4, h = bh & 15;
  unsigned short* crow = ctx + ((size_t)(s0w + q) * 2 + b) * 2048 + h * 128;
#pragma unroll
  for (int d4 = 0; d4 < 4; ++d4)
#pragma unroll
    for (int rq = 0; rq < 4; ++rq) {
      ushort4 o;
      o.x = f2bf(acc[d4][rq * 4 + 0] * inv);
      o.y = f2bf(acc[d4][rq * 4 + 1] * inv);
      o.z = f2bf(acc[d4][rq * 4 + 2] * inv);
      o.w = f2bf(acc[d4][rq * 4 + 3] * inv);
      *(ushort4*)(crow + d4 * 32 + rq * 8 + hi * 4) = o;
    }
}

// ---------------------------------------------------------------------------
extern "C" void kernel_launch(void* const* d_in, const int* in_sizes, int n_in,
                              void* d_out, int out_size, void* d_ws, size_t ws_size,
                              hipStream_t stream) {
  const float* x    = (const float*)d_in[0];
  const float* kc   = (const float*)d_in[1];
  const float* vc   = (const float*)d_in[2];
  const float* mask = (const float*)d_in[3];
  const float* q_w  = (const float*)d_in[4];
  const float* q_b  = (const float*)d_in[5];
  const float* k_w  = (const float*)d_in[6];
  const float* k_b  = (const float*)d_in[7];
  const float* v_w  = (const float*)d_in[8];
  const float* v_b  = (const float*)d_in[9];
  const float* o_w  = (const float*)d_in[10];
  const float* o_b  = (const float*)d_in[11];
  const float* ln1g = (const float*)d_in[12];
  const float* ln1b = (const float*)d_in[13];
  const float* ln2g = (const float*)d_in[14];
  const float* ln2b = (const float*)d_in[15];
  const float* w1   = (const float*)d_in[16];
  const float* b1   = (const float*)d_in[17];
  const float* w2   = (const float*)d_in[18];
  const float* b2   = (const float*)d_in[19];

  float* out_x = (float*)d_out;                       // [S,B,D]
  float* out_k = out_x + (size_t)8388608;             // [T,B,H,hd]
  float* out_v = out_k + (size_t)16777216;            // [T,B,H,hd]

  char* ws = (char*)d_ws;
  unsigned short* kf  = (unsigned short*)(ws);                  // bf16 [B,H,T,hd]
  unsigned short* vft = (unsigned short*)(ws + 33554432);       // bf16 [B,H,hd,T]
  unsigned short* Wt  = (unsigned short*)(ws + 67108864);       // bf16 [8192,2048]
  float*          x1  = (float*)(ws + 100663296);               // fp32 [4096,2048]
  unsigned short* mid = (unsigned short*)ws;                    // bf16 [4096,8192]
  u32* mflags = (u32*)(ws + 100663296);                         // 256 u32 flags

  unsigned short* xn  = (unsigned short*)d_out;                 // bf16 [4096,2048]
  unsigned short* ctx = xn;                                     // bf16 [4096,2048]
  unsigned short* qb  = (unsigned short*)((char*)d_out + 16777216); // [B,H,S,hd]
  unsigned short* hn  = qb;                                     // reuse after attn

  const bool bigws = ws_size >= (size_t)167772160;              // >= 160 MiB
  unsigned short* w2t = bigws ? (unsigned short*)(ws + 134217728) : Wt;

  const dim3 b256(256);

  prep_k<<<37120, b256, 0, stream>>>(x, ln1g, ln1b, xn, kc, kf, out_k,
                                     vc, vft, out_v, mask, mflags,
                                     q_w, k_w, v_w, o_w, Wt);

  gemm8p<0, 0><<<384, dim3(512), 0, stream>>>(
      xn, Wt, q_b, k_b, v_b, out_k, qb, out_v, kf, vft, 6144, 2048);

  attn6<<<512, b256, 0, stream>>>(qb, kf, vft, mask, mflags, ctx);

  gemm8n<1, 1><<<256, dim3(512), 0, stream>>>(
      ctx, Wt + (size_t)6144 * 2048, o_b, x, x1, 2048, 2048);

  prep2_k<<<bigws ? 36864 : 20480, b256, 0, stream>>>(
      x1, ln2g, ln2b, hn, w1, Wt, w2, w2t);

  gemm8p<2, 2><<<512, dim3(512), 0, stream>>>(
      hn, Wt, b1, nullptr, nullptr, nullptr, mid, nullptr, nullptr, nullptr,
      8192, 2048);

  if (!bigws) wconvT<<<dim3(256, 64), b256, 0, stream>>>(w2, Wt, 8192, 2048);

  gemm8n<3, 1><<<256, dim3(512), 0, stream>>>(
      mid, w2t, b2, x1, out_x, 2048, 8192);
}